// Round 1
// baseline (1141.065 us; speedup 1.0000x reference)
//
#include <hip/hip_runtime.h>
#include <stdint.h>
#include <stddef.h>

#define B_ 4
#define C_ 2048
#define D_ 1024
#define FFN_ 2560
#define ROWS_ 8192   // B_*C_

typedef unsigned short u16;
typedef short bf16x8 __attribute__((ext_vector_type(8)));
typedef float f32x4 __attribute__((ext_vector_type(4)));

__device__ __forceinline__ float bf2f(u16 x){ union { unsigned u; float f; } v; v.u = ((unsigned)x)<<16; return v.f; }
__device__ __forceinline__ u16 f2bf(float f){ union { float f; unsigned u; } v; v.f = f; unsigned r = v.u + 0x7fffu + ((v.u>>16)&1u); return (u16)(r>>16); }
__device__ __forceinline__ float sigm_(float x){ return 1.f/(1.f+__expf(-x)); }
__device__ __forceinline__ float silu_(float x){ return x/(1.f+__expf(-x)); }
__device__ __forceinline__ float softplus_(float x){ return (x>15.f)? x : log1pf(__expf(x)); }

// ---------------- async global->LDS (16B per lane, wave-uniform LDS base) ---
__device__ __forceinline__ void async16(u16* lds_base, const u16* g){
  __builtin_amdgcn_global_load_lds((const __attribute__((address_space(1))) unsigned int*)g,
                                   (__attribute__((address_space(3))) unsigned int*)lds_base,
                                   16, 0, 0);
}

// ---------------- GEMM: C(MxN) = A(MxK,row-major bf16) * Bt(NxK,row-major bf16)^T
#define EPI_BF16  0
#define EPI_DT    1
#define EPI_MOM   2
#define EPI_SILU  3
#define EPI_MULG  4
#define EPI_TRANS 5
#define EPI_ADDX  6
#define EPI_DELTA 7

template<int EPI>
__global__ __launch_bounds__(256)
void gemm128(const u16* __restrict__ A, const u16* __restrict__ Bt,
             int M, int N, int K,
             float* __restrict__ f0, float* __restrict__ f1,
             const float* __restrict__ c0, const float* __restrict__ c1, const float* __restrict__ c2,
             u16* __restrict__ h0, const u16* __restrict__ h1)
{
  __shared__ u16 As[128*32];
  __shared__ u16 Bs[128*32];
  const int tid  = threadIdx.x;
  const int wave = tid>>6, lane = tid&63;
  const int bm = blockIdx.y*128, bn = blockIdx.x*128;
  // staging: 8 chunks of 1KB per tile; wave w does chunks 2w,2w+1 of each
  const int srow = wave*32 + (lane>>2);      // j=0 row; j=1 adds 16
  const int scol = (lane&3)*8;
  const u16* aG0 = A  + (size_t)(bm + srow)*K + scol;
  const u16* aG1 = aG0 + (size_t)16*K;
  const u16* bG0 = Bt + (size_t)(bn + srow)*K + scol;
  const u16* bG1 = bG0 + (size_t)16*K;
  u16* aL0 = As + (wave*2+0)*512;
  u16* aL1 = As + (wave*2+1)*512;
  u16* bL0 = Bs + (wave*2+0)*512;
  u16* bL1 = Bs + (wave*2+1)*512;
  const int wr = wave>>1, wc = wave&1;
  const int mrow = lane&15, quad = lane>>4;

  f32x4 acc[4][4];
  #pragma unroll
  for (int i=0;i<4;i++)
    #pragma unroll
    for (int j=0;j<4;j++) acc[i][j] = (f32x4){0.f,0.f,0.f,0.f};

  for (int k0=0; k0<K; k0+=32){
    __syncthreads();
    async16(aL0, aG0 + k0);
    async16(aL1, aG1 + k0);
    async16(bL0, bG0 + k0);
    async16(bL1, bG1 + k0);
    __syncthreads();
    bf16x8 af[4], bfv[4];
    #pragma unroll
    for (int i=0;i<4;i++) af[i]  = *(const bf16x8*)(As + (wr*64+i*16+mrow)*32 + quad*8);
    #pragma unroll
    for (int j=0;j<4;j++) bfv[j] = *(const bf16x8*)(Bs + (wc*64+j*16+mrow)*32 + quad*8);
    #pragma unroll
    for (int i=0;i<4;i++)
      #pragma unroll
      for (int j=0;j<4;j++)
        acc[i][j] = __builtin_amdgcn_mfma_f32_16x16x32_bf16(af[i], bfv[j], acc[i][j], 0,0,0);
  }

  // epilogue: tile (i,j): rows bm+wr*64+i*16+quad*4+t (t=0..3), col bn+wc*64+j*16+mrow
  #pragma unroll
  for (int i=0;i<4;i++){
    const int row0 = bm + wr*64 + i*16 + quad*4;
    #pragma unroll
    for (int j=0;j<4;j++){
      const int col = bn + wc*64 + j*16 + mrow;
      f32x4 v = acc[i][j];
      if constexpr (EPI == EPI_TRANS){
        ushort4 p; p.x=f2bf(v[0]); p.y=f2bf(v[1]); p.z=f2bf(v[2]); p.w=f2bf(v[3]);
        *(ushort4*)(h0 + (size_t)col*M + row0) = p;
      } else if constexpr (EPI == EPI_BF16){
        #pragma unroll
        for (int t=0;t<4;t++) h0[(size_t)(row0+t)*N + col] = f2bf(v[t]);
      } else if constexpr (EPI == EPI_DT){
        const float b = c0[col];
        #pragma unroll
        for (int t=0;t<4;t++) f0[(size_t)(row0+t)*N + col] = softplus_(v[t]+b);
      } else if constexpr (EPI == EPI_MOM){
        const float beta = sigm_(c2[0]);
        #pragma unroll
        for (int t=0;t<4;t++){
          size_t idx = (size_t)(row0+t)*N + col;
          float vel = beta*c0[idx] + v[t];
          f0[idx] = vel;
          f1[idx] = c1[idx] + vel;
        }
      } else if constexpr (EPI == EPI_SILU){
        #pragma unroll
        for (int t=0;t<4;t++) h0[(size_t)(row0+t)*N + col] = f2bf(silu_(v[t]));
      } else if constexpr (EPI == EPI_MULG){
        #pragma unroll
        for (int t=0;t<4;t++){
          size_t idx = (size_t)(row0+t)*N + col;
          h0[idx] = f2bf(v[t]*bf2f(h1[idx]));
        }
      } else if constexpr (EPI == EPI_ADDX){
        #pragma unroll
        for (int t=0;t<4;t++){
          size_t idx = (size_t)(row0+t)*N + col;
          f0[idx] = f0[idx] + v[t];
        }
      } else if constexpr (EPI == EPI_DELTA){
        const float g = sigm_(c1[0]);
        const float e = softplus_(c2[0])*0.25f;
        #pragma unroll
        for (int t=0;t<4;t++){
          size_t idx = (size_t)(row0+t)*N + col;
          f0[idx] = g*c0[idx] + e*v[t];
        }
      }
    }
  }
}

// ---------------- transpose + f32->bf16 weight conversion (W: KxN -> Wt: NxK)
__global__ void transpose_cvt(const float* __restrict__ W, u16* __restrict__ Wt, int K, int N)
{
  __shared__ float tile[32][33];
  const int tx = threadIdx.x, ty = threadIdx.y;
  const int c0 = blockIdx.x*32, r0 = blockIdx.y*32;
  #pragma unroll
  for (int i=0;i<4;i++) tile[ty+8*i][tx] = W[(size_t)(r0+ty+8*i)*N + c0+tx];
  __syncthreads();
  #pragma unroll
  for (int i=0;i<4;i++) Wt[(size_t)(c0+ty+8*i)*K + r0+tx] = f2bf(tile[tx][ty+8*i]);
}

// W_eff = ffn_down + delta_W, transposed: (2560x1024) -> (1024x2560) bf16
__global__ void weff_transpose(const float* __restrict__ Wa, const float* __restrict__ Wb, u16* __restrict__ Wt)
{
  __shared__ float tile[32][33];
  const int tx = threadIdx.x, ty = threadIdx.y;
  const int c0 = blockIdx.x*32, r0 = blockIdx.y*32;  // c: 0..1023, r: 0..2559
  #pragma unroll
  for (int i=0;i<4;i++){
    size_t idx = (size_t)(r0+ty+8*i)*1024 + c0+tx;
    tile[ty+8*i][tx] = Wa[idx] + Wb[idx];
  }
  __syncthreads();
  #pragma unroll
  for (int i=0;i<4;i++) Wt[(size_t)(c0+ty+8*i)*2560 + r0+tx] = f2bf(tile[tx][ty+8*i]);
}

// bf16 transpose (in: R x Cc -> out: Cc x R)
__global__ void transpose_bf16(const u16* __restrict__ in, u16* __restrict__ out, int R, int Cc)
{
  __shared__ u16 tile[32][33];
  const int tx = threadIdx.x, ty = threadIdx.y;
  const int c0 = blockIdx.x*32, r0 = blockIdx.y*32;
  #pragma unroll
  for (int i=0;i<4;i++) tile[ty+8*i][tx] = in[(size_t)(r0+ty+8*i)*Cc + c0+tx];
  __syncthreads();
  #pragma unroll
  for (int i=0;i<4;i++) out[(size_t)(c0+ty+8*i)*R + r0+tx] = tile[tx][ty+8*i];
}

__global__ void cvt_bf16x4(const float* __restrict__ in, u16* __restrict__ out, int n4)
{
  int i = blockIdx.x*256 + threadIdx.x;
  if (i < n4){
    float4 v = ((const float4*)in)[i];
    ushort4 p; p.x=f2bf(v.x); p.y=f2bf(v.y); p.z=f2bf(v.z); p.w=f2bf(v.w);
    ((ushort4*)out)[i] = p;
  }
}

__global__ void atab_k(const float* __restrict__ A_log, float* __restrict__ A_tab)
{
  int i = blockIdx.x*256 + threadIdx.x;
  if (i < 512*16) A_tab[i] = -__expf(A_log[i]);
}

// RMSNorm over rows of 1024 f32 -> bf16
__global__ __launch_bounds__(256) void rmsnorm_k(const float* __restrict__ x, const float* __restrict__ w, u16* __restrict__ out)
{
  const int row = blockIdx.x, tid = threadIdx.x;
  float4 v = ((const float4*)(x + (size_t)row*1024))[tid];
  float s = v.x*v.x + v.y*v.y + v.z*v.z + v.w*v.w;
  #pragma unroll
  for (int o=32;o>0;o>>=1) s += __shfl_down(s, o);
  __shared__ float red[4];
  const int wave = tid>>6, lane = tid&63;
  if (lane==0) red[wave] = s;
  __syncthreads();
  float tot = red[0]+red[1]+red[2]+red[3];
  float sc = rsqrtf(tot*(1.f/1024.f) + 1e-6f);
  float4 wv = ((const float4*)w)[tid];
  ushort4 p; p.x=f2bf(v.x*sc*wv.x); p.y=f2bf(v.y*sc*wv.y); p.z=f2bf(v.z*sc*wv.z); p.w=f2bf(v.w*sc*wv.w);
  ((ushort4*)(out + (size_t)row*1024))[tid] = p;
}

// B/C projections: BCs (8192 x 32) = [xn@ssm_B_w | xn@ssm_C_w]
__global__ __launch_bounds__(256) void bc_proj(const u16* __restrict__ xn, const float* __restrict__ Bw,
                                               const float* __restrict__ Cw, float* __restrict__ BCs)
{
  const int t = threadIdx.x;
  const int row = blockIdx.x*8 + (t>>5);
  const int c = t & 31;
  const float* w = (c<16) ? Bw : Cw;
  const int cc = c & 15;
  const u16* ar = xn + (size_t)row*1024;
  float acc = 0.f;
  #pragma unroll 8
  for (int k=0;k<1024;k++) acc += bf2f(ar[k]) * w[k*16+cc];
  BCs[(size_t)row*32 + c] = acc;
}

// depthwise causal conv (K=4) + silu gate -> mixed cols 0..511
__global__ __launch_bounds__(256) void conv_k(const u16* __restrict__ P1, const float* __restrict__ kw, u16* __restrict__ mixed)
{
  const int idx = blockIdx.x*256 + threadIdx.x;   // B*C*512
  const int c = idx & 511;
  const int t = (idx>>9) & 2047;
  const int b = idx >> 20;
  const size_t rowb = (size_t)b*2048;
  float g = bf2f(P1[(rowb+t)*1024 + c]);
  float acc = 0.f;
  #pragma unroll
  for (int k=0;k<4;k++){
    int tt = t-3+k;
    if (tt>=0) acc += bf2f(P1[(rowb+tt)*1024 + 512 + c]) * kw[k*512+c];
  }
  mixed[(rowb+t)*1024 + c] = f2bf(silu_(g)*acc);
}

// chunked selective scan: 16 chunks of 128
__global__ __launch_bounds__(256) void scan_p1(const float* __restrict__ dt, const u16* __restrict__ P2,
                                               const float* __restrict__ BCs, const float* __restrict__ A_tab,
                                               float* __restrict__ hend, float* __restrict__ aprod)
{
  const int d = blockIdx.x*256 + threadIdx.x;
  const int ch = blockIdx.y, b = blockIdx.z;
  float Ar[16], h[16], ap[16];
  #pragma unroll
  for (int s=0;s<16;s++){ Ar[s] = A_tab[d*16+s]; h[s]=0.f; ap[s]=1.f; }
  const int t0 = ch*128;
  for (int t=0;t<128;t++){
    size_t row = (size_t)b*2048 + t0 + t;
    float dtv = dt[row*512 + d];
    float u = bf2f(P2[row*1024 + d]);
    float du = dtv*u;
    const float* bs = BCs + row*32;
    #pragma unroll
    for (int s=0;s<16;s++){
      float dA = __expf(dtv*Ar[s]);
      h[s] = dA*h[s] + du*bs[s];
      ap[s] *= dA;
    }
  }
  size_t o = ((size_t)((b*512+d)*16 + ch))*16;
  #pragma unroll
  for (int s=0;s<16;s++){ hend[o+s]=h[s]; aprod[o+s]=ap[s]; }
}

__global__ __launch_bounds__(256) void scan_p2(const float* __restrict__ hend, const float* __restrict__ aprod,
                                               float* __restrict__ hin)
{
  const int g = blockIdx.x*256 + threadIdx.x;   // 32768 = (b*512+d)*16+s
  const int s = g & 15, bd = g >> 4;
  float h = 0.f;
  for (int ch=0; ch<16; ch++){
    size_t o = ((size_t)(bd*16+ch))*16 + s;
    hin[o] = h;
    h = aprod[o]*h + hend[o];
  }
}

__global__ __launch_bounds__(256) void scan_p3(const float* __restrict__ dt, const u16* __restrict__ P2,
                                               const float* __restrict__ BCs, const float* __restrict__ A_tab,
                                               const float* __restrict__ hin, const float* __restrict__ Dp,
                                               u16* __restrict__ mixed)
{
  const int d = blockIdx.x*256 + threadIdx.x;
  const int ch = blockIdx.y, b = blockIdx.z;
  float Ar[16], h[16];
  size_t o = ((size_t)((b*512+d)*16 + ch))*16;
  #pragma unroll
  for (int s=0;s<16;s++){ Ar[s] = A_tab[d*16+s]; h[s] = hin[o+s]; }
  const float Dd = Dp[d];
  const int t0 = ch*128;
  for (int t=0;t<128;t++){
    size_t row = (size_t)b*2048 + t0 + t;
    float dtv = dt[row*512 + d];
    float u = bf2f(P2[row*1024 + d]);
    float zv = bf2f(P2[row*1024 + 512 + d]);
    float du = dtv*u;
    const float* bs = BCs + row*32;
    const float* cs = bs + 16;
    float y = 0.f;
    #pragma unroll
    for (int s=0;s<16;s++){
      float dA = __expf(dtv*Ar[s]);
      h[s] = dA*h[s] + du*bs[s];
      y += h[s]*cs[s];
    }
    float outv = (y + Dd*u)*silu_(zv);
    mixed[row*1024 + 512 + d] = f2bf(outv);
  }
}

extern "C" void kernel_launch(void* const* d_in, const int* in_sizes, int n_in,
                              void* d_out, int out_size, void* d_ws, size_t ws_size,
                              hipStream_t stream)
{
  const float* x          = (const float*)d_in[0];
  const float* velocity   = (const float*)d_in[1];
  const float* v_hat      = (const float*)d_in[2];
  const float* delta_W    = (const float*)d_in[3];
  const float* pre_norm_w = (const float*)d_in[4];
  const float* ffn_norm_w = (const float*)d_in[5];
  const float* conv_in_w  = (const float*)d_in[6];
  const float* conv_kw    = (const float*)d_in[7];
  const float* ssm_in_w   = (const float*)d_in[8];
  const float* ssm_dt_w   = (const float*)d_in[9];
  const float* ssm_dt_b   = (const float*)d_in[10];
  const float* ssm_A_log  = (const float*)d_in[11];
  const float* ssm_B_w    = (const float*)d_in[12];
  const float* ssm_C_w    = (const float*)d_in[13];
  const float* ssm_D      = (const float*)d_in[14];
  const float* out_proj_w = (const float*)d_in[15];
  const float* log_beta   = (const float*)d_in[16];
  const float* gate_up_w  = (const float*)d_in[17];
  const float* ffn_down_w = (const float*)d_in[18];
  const float* ffn_tgt_w  = (const float*)d_in[19];
  const float* log_gamma  = (const float*)d_in[20];
  const float* log_eta    = (const float*)d_in[21];

  float* out_x     = (float*)d_out;
  float* out_vel   = out_x + (size_t)ROWS_*D_;
  float* out_delta = out_vel + (size_t)ROWS_*D_;

  char* wsp = (char*)d_ws;
  size_t off = 0;
  auto alloc = [&](size_t bytes)->char*{ char* p = wsp + off; off += (bytes + 255) & ~(size_t)255; return p; };

  u16* conv_in_t  = (u16*)alloc((size_t)1024*1024*2);
  u16* ssm_in_t   = (u16*)alloc((size_t)1024*1024*2);
  u16* ssm_dt_t   = (u16*)alloc((size_t)512*1024*2);
  u16* out_proj_t = (u16*)alloc((size_t)1024*1024*2);
  u16* gate_up_t  = (u16*)alloc((size_t)5120*1024*2);
  u16* target_t   = (u16*)alloc((size_t)2560*1024*2);
  u16* weff_t     = (u16*)alloc((size_t)1024*2560*2);
  float* A_tab    = (float*)alloc((size_t)512*16*4);
  u16* xn         = (u16*)alloc((size_t)ROWS_*1024*2);
  u16* P1         = (u16*)alloc((size_t)ROWS_*1024*2);
  u16* P2         = (u16*)alloc((size_t)ROWS_*1024*2);
  float* dtbuf    = (float*)alloc((size_t)ROWS_*512*4);
  float* BCs      = (float*)alloc((size_t)ROWS_*32*4);
  float* hend     = (float*)alloc((size_t)4*512*16*16*4);
  float* aprod    = (float*)alloc((size_t)4*512*16*16*4);
  float* hin      = (float*)alloc((size_t)4*512*16*16*4);
  u16* mixed      = (u16*)alloc((size_t)ROWS_*1024*2);
  u16* ffn_in     = (u16*)alloc((size_t)ROWS_*1024*2);
  u16* zbuf       = (u16*)alloc((size_t)ROWS_*2560*2);
  u16* T1t        = (u16*)alloc((size_t)2560*ROWS_*2);
  u16* ffn_inT    = xn;   // reuse: xn dead after the 4 input projections
  u16* vhat_bf    = P1;   // reuse: P1 dead after conv (convert v_hat after conv)

  dim3 tb(32,8);
  // weight prep
  transpose_cvt<<<dim3(32,32),  tb, 0, stream>>>(conv_in_w,  conv_in_t, 1024, 1024);
  transpose_cvt<<<dim3(32,32),  tb, 0, stream>>>(ssm_in_w,   ssm_in_t,  1024, 1024);
  transpose_cvt<<<dim3(16,32),  tb, 0, stream>>>(ssm_dt_w,   ssm_dt_t,  1024, 512);
  transpose_cvt<<<dim3(32,32),  tb, 0, stream>>>(out_proj_w, out_proj_t,1024, 1024);
  transpose_cvt<<<dim3(160,32), tb, 0, stream>>>(gate_up_w,  gate_up_t, 1024, 5120);
  transpose_cvt<<<dim3(80,32),  tb, 0, stream>>>(ffn_tgt_w,  target_t,  1024, 2560);
  weff_transpose<<<dim3(32,80), tb, 0, stream>>>(ffn_down_w, delta_W, weff_t);
  atab_k<<<32, 256, 0, stream>>>(ssm_A_log, A_tab);

  // pre-norm + input projections
  rmsnorm_k<<<ROWS_, 256, 0, stream>>>(x, pre_norm_w, xn);
  gemm128<EPI_BF16><<<dim3(8,64), 256, 0, stream>>>(xn, conv_in_t, ROWS_,1024,1024,
      nullptr,nullptr,nullptr,nullptr,nullptr, P1, nullptr);
  gemm128<EPI_BF16><<<dim3(8,64), 256, 0, stream>>>(xn, ssm_in_t, ROWS_,1024,1024,
      nullptr,nullptr,nullptr,nullptr,nullptr, P2, nullptr);
  gemm128<EPI_DT><<<dim3(4,64), 256, 0, stream>>>(xn, ssm_dt_t, ROWS_,512,1024,
      dtbuf,nullptr, ssm_dt_b,nullptr,nullptr, nullptr,nullptr);
  bc_proj<<<1024, 256, 0, stream>>>(xn, ssm_B_w, ssm_C_w, BCs);

  // conv branch + ssm branch -> mixed
  conv_k<<<16384, 256, 0, stream>>>(P1, conv_kw, mixed);
  scan_p1<<<dim3(2,16,4), 256, 0, stream>>>(dtbuf, P2, BCs, A_tab, hend, aprod);
  scan_p2<<<128, 256, 0, stream>>>(hend, aprod, hin);
  scan_p3<<<dim3(2,16,4), 256, 0, stream>>>(dtbuf, P2, BCs, A_tab, hin, ssm_D, mixed);

  // out_proj + momentum residual -> velocity (d_out), x_new (d_out slice 0)
  gemm128<EPI_MOM><<<dim3(8,64), 256, 0, stream>>>(mixed, out_proj_t, ROWS_,1024,1024,
      out_vel, out_x, velocity, x, log_beta, nullptr,nullptr);

  // FFN
  rmsnorm_k<<<ROWS_, 256, 0, stream>>>(out_x, ffn_norm_w, ffn_in);
  transpose_bf16<<<dim3(32,256), tb, 0, stream>>>(ffn_in, ffn_inT, ROWS_, 1024);
  cvt_bf16x4<<<8192, 256, 0, stream>>>(v_hat, vhat_bf, ROWS_*1024/4);

  gemm128<EPI_SILU><<<dim3(20,64), 256, 0, stream>>>(ffn_in, gate_up_t, ROWS_,2560,1024,
      nullptr,nullptr,nullptr,nullptr,nullptr, zbuf, nullptr);
  gemm128<EPI_MULG><<<dim3(20,64), 256, 0, stream>>>(ffn_in, gate_up_t + (size_t)2560*1024, ROWS_,2560,1024,
      nullptr,nullptr,nullptr,nullptr,nullptr, zbuf, zbuf);
  gemm128<EPI_TRANS><<<dim3(20,64), 256, 0, stream>>>(vhat_bf, target_t, ROWS_,2560,1024,
      nullptr,nullptr,nullptr,nullptr,nullptr, T1t, nullptr);

  // down-proj (fused fast-weight) -> final x
  gemm128<EPI_ADDX><<<dim3(8,64), 256, 0, stream>>>(zbuf, weff_t, ROWS_,1024,2560,
      out_x,nullptr,nullptr,nullptr,nullptr, nullptr,nullptr);

  // delta_W update: update = T1^T @ ffn_in / B
  gemm128<EPI_DELTA><<<dim3(8,20), 256, 0, stream>>>(T1t, ffn_inT, 2560,1024,ROWS_,
      out_delta,nullptr, delta_W, log_gamma, log_eta, nullptr,nullptr);
}

// Round 2
// 979.509 us; speedup vs baseline: 1.1649x; 1.1649x over previous
//
#include <hip/hip_runtime.h>
#include <stdint.h>
#include <stddef.h>

#define B_ 4
#define C_ 2048
#define D_ 1024
#define FFN_ 2560
#define ROWS_ 8192   // B_*C_

typedef unsigned short u16;
typedef short bf16x8 __attribute__((ext_vector_type(8)));
typedef float f32x4 __attribute__((ext_vector_type(4)));

__device__ __forceinline__ float bf2f(u16 x){ union { unsigned u; float f; } v; v.u = ((unsigned)x)<<16; return v.f; }
__device__ __forceinline__ u16 f2bf(float f){ union { float f; unsigned u; } v; v.f = f; unsigned r = v.u + 0x7fffu + ((v.u>>16)&1u); return (u16)(r>>16); }
__device__ __forceinline__ float sigm_(float x){ return 1.f/(1.f+__expf(-x)); }
__device__ __forceinline__ float silu_(float x){ return x/(1.f+__expf(-x)); }
__device__ __forceinline__ float softplus_(float x){ return (x>15.f)? x : log1pf(__expf(x)); }

__device__ __forceinline__ void async16(u16* lds_base, const u16* g){
  __builtin_amdgcn_global_load_lds((const __attribute__((address_space(1))) unsigned int*)g,
                                   (__attribute__((address_space(3))) unsigned int*)lds_base,
                                   16, 0, 0);
}

// ---------------- GEMM: C(MxN) = A(MxK,row-major bf16) * Bt(NxK,row-major bf16)^T
// Split-K via blockIdx.z * ksplit.
#define EPI_INPROJ 0
#define EPI_MOM    1
#define EPI_SWIGLU 2
#define EPI_TRANS  3
#define EPI_ATOMX  4
#define EPI_ATOMD  5

template<int EPI>
__global__ __launch_bounds__(256)
void gemm128(const u16* __restrict__ A, const u16* __restrict__ Bt,
             int M, int N, int K, int ksplit,
             float* __restrict__ f0, float* __restrict__ f1,
             const float* __restrict__ c0, const float* __restrict__ c1, const float* __restrict__ c2,
             u16* __restrict__ h0, u16* __restrict__ h1)
{
  __shared__ u16 As[128*32];
  __shared__ u16 Bs[128*32];
  const int tid  = threadIdx.x;
  const int wave = tid>>6, lane = tid&63;
  const int bm = blockIdx.y*128, bn = blockIdx.x*128;
  const int srow = wave*32 + (lane>>2);
  const int scol = (lane&3)*8;
  const u16* aG0 = A  + (size_t)(bm + srow)*K + scol;
  const u16* aG1 = aG0 + (size_t)16*K;
  const u16* bG0 = Bt + (size_t)(bn + srow)*K + scol;
  const u16* bG1 = bG0 + (size_t)16*K;
  u16* aL0 = As + (wave*2+0)*512;
  u16* aL1 = As + (wave*2+1)*512;
  u16* bL0 = Bs + (wave*2+0)*512;
  u16* bL1 = Bs + (wave*2+1)*512;
  const int wr = wave>>1, wc = wave&1;
  const int mrow = lane&15, quad = lane>>4;

  f32x4 acc[4][4];
  #pragma unroll
  for (int i=0;i<4;i++)
    #pragma unroll
    for (int j=0;j<4;j++) acc[i][j] = (f32x4){0.f,0.f,0.f,0.f};

  const int kbeg = blockIdx.z * ksplit;
  const int kend = kbeg + ksplit;
  for (int k0=kbeg; k0<kend; k0+=32){
    __syncthreads();
    async16(aL0, aG0 + k0);
    async16(aL1, aG1 + k0);
    async16(bL0, bG0 + k0);
    async16(bL1, bG1 + k0);
    __syncthreads();
    bf16x8 af[4], bfv[4];
    #pragma unroll
    for (int i=0;i<4;i++) af[i]  = *(const bf16x8*)(As + (wr*64+i*16+mrow)*32 + quad*8);
    #pragma unroll
    for (int j=0;j<4;j++) bfv[j] = *(const bf16x8*)(Bs + (wc*64+j*16+mrow)*32 + quad*8);
    #pragma unroll
    for (int i=0;i<4;i++)
      #pragma unroll
      for (int j=0;j<4;j++)
        acc[i][j] = __builtin_amdgcn_mfma_f32_16x16x32_bf16(af[i], bfv[j], acc[i][j], 0,0,0);
  }

  #pragma unroll
  for (int i=0;i<4;i++){
    const int row0 = bm + wr*64 + i*16 + quad*4;
    #pragma unroll
    for (int j=0;j<4;j++){
      const int col = bn + wc*64 + j*16 + mrow;
      f32x4 v = acc[i][j];
      if constexpr (EPI == EPI_INPROJ){
        // N=2688: [0,1024) -> P1 bf16 (h0); [1024,2048) -> P2 bf16 (h1);
        // [2048,2560) -> dt f32 softplus+bias (f0); [2560,2592) -> BCs f32 (f1)
        if (col < 1024){
          #pragma unroll
          for (int t=0;t<4;t++) h0[(size_t)(row0+t)*1024 + col] = f2bf(v[t]);
        } else if (col < 2048){
          #pragma unroll
          for (int t=0;t<4;t++) h1[(size_t)(row0+t)*1024 + (col-1024)] = f2bf(v[t]);
        } else if (col < 2560){
          const float b = c0[col-2048];
          #pragma unroll
          for (int t=0;t<4;t++) f0[(size_t)(row0+t)*512 + (col-2048)] = softplus_(v[t]+b);
        } else {
          const int cl = col - 2560;
          if (cl < 32){
            #pragma unroll
            for (int t=0;t<4;t++) f1[(size_t)(row0+t)*32 + cl] = v[t];
          }
        }
      } else if constexpr (EPI == EPI_MOM){
        const float beta = sigm_(c2[0]);
        #pragma unroll
        for (int t=0;t<4;t++){
          size_t idx = (size_t)(row0+t)*N + col;
          float vel = beta*c0[idx] + v[t];
          f0[idx] = vel;
          f1[idx] = c1[idx] + vel;
        }
      } else if constexpr (EPI == EPI_SWIGLU){
        // interleaved weight rows: even col = gate(col/2), odd col = up(col/2)
        float pv[4];
        #pragma unroll
        for (int t=0;t<4;t++) pv[t] = __shfl_xor(v[t], 1, 64);
        if (!(mrow & 1)){
          const int o = col >> 1;     // [0,2560)
          #pragma unroll
          for (int t=0;t<4;t++) h0[(size_t)(row0+t)*2560 + o] = f2bf(silu_(v[t])*pv[t]);
        }
      } else if constexpr (EPI == EPI_TRANS){
        ushort4 p; p.x=f2bf(v[0]); p.y=f2bf(v[1]); p.z=f2bf(v[2]); p.w=f2bf(v[3]);
        *(ushort4*)(h0 + (size_t)col*M + row0) = p;
      } else if constexpr (EPI == EPI_ATOMX){
        #pragma unroll
        for (int t=0;t<4;t++) atomicAdd(&f0[(size_t)(row0+t)*N + col], v[t]);
      } else if constexpr (EPI == EPI_ATOMD){
        const float e = softplus_(c2[0])*0.25f;
        #pragma unroll
        for (int t=0;t<4;t++) atomicAdd(&f0[(size_t)(row0+t)*N + col], e*v[t]);
      }
    }
  }
}

// ---------------- transpose + f32->bf16 weight conversion (W: KxN -> Wt: NxK)
__global__ void transpose_cvt(const float* __restrict__ W, u16* __restrict__ Wt, int K, int N)
{
  __shared__ float tile[32][33];
  const int tx = threadIdx.x, ty = threadIdx.y;
  const int c0 = blockIdx.x*32, r0 = blockIdx.y*32;
  #pragma unroll
  for (int i=0;i<4;i++) tile[ty+8*i][tx] = W[(size_t)(r0+ty+8*i)*N + c0+tx];
  __syncthreads();
  #pragma unroll
  for (int i=0;i<4;i++) Wt[(size_t)(c0+ty+8*i)*K + r0+tx] = f2bf(tile[tx][ty+8*i]);
}

// gate_up (1024x5120) -> interleaved-transposed (5120x1024): row 2p = gate col p, row 2p+1 = up col p
__global__ void transpose_cvt_gu(const float* __restrict__ W, u16* __restrict__ Wt)
{
  __shared__ float tile[32][33];
  const int tx = threadIdx.x, ty = threadIdx.y;
  const int c0 = blockIdx.x*32, r0 = blockIdx.y*32;
  #pragma unroll
  for (int i=0;i<4;i++) tile[ty+8*i][tx] = W[(size_t)(r0+ty+8*i)*5120 + c0+tx];
  __syncthreads();
  #pragma unroll
  for (int i=0;i<4;i++){
    const int c = c0+ty+8*i;
    const int n = (c < 2560) ? (c*2) : ((c-2560)*2+1);
    Wt[(size_t)n*1024 + r0+tx] = f2bf(tile[tx][ty+8*i]);
  }
}

// B/C weights (1024x16 each) -> rows [2560,2688) of combined in-proj weight, zero-padded
__global__ void bcw_cvt(const float* __restrict__ Bw, const float* __restrict__ Cw, u16* __restrict__ out)
{
  int i = blockIdx.x*256 + threadIdx.x;   // 128*1024
  int r = i >> 10, k = i & 1023;
  float v = 0.f;
  if (r < 16) v = Bw[k*16 + r];
  else if (r < 32) v = Cw[k*16 + (r-16)];
  out[(size_t)r*1024 + k] = f2bf(v);
}

// W_eff = ffn_down + delta_W, transposed: (2560x1024) -> (1024x2560) bf16
__global__ void weff_transpose(const float* __restrict__ Wa, const float* __restrict__ Wb, u16* __restrict__ Wt)
{
  __shared__ float tile[32][33];
  const int tx = threadIdx.x, ty = threadIdx.y;
  const int c0 = blockIdx.x*32, r0 = blockIdx.y*32;
  #pragma unroll
  for (int i=0;i<4;i++){
    size_t idx = (size_t)(r0+ty+8*i)*1024 + c0+tx;
    tile[ty+8*i][tx] = Wa[idx] + Wb[idx];
  }
  __syncthreads();
  #pragma unroll
  for (int i=0;i<4;i++) Wt[(size_t)(c0+ty+8*i)*2560 + r0+tx] = f2bf(tile[tx][ty+8*i]);
}

// bf16 transpose (in: R x Cc -> out: Cc x R)
__global__ void transpose_bf16(const u16* __restrict__ in, u16* __restrict__ out, int R, int Cc)
{
  __shared__ u16 tile[32][33];
  const int tx = threadIdx.x, ty = threadIdx.y;
  const int c0 = blockIdx.x*32, r0 = blockIdx.y*32;
  #pragma unroll
  for (int i=0;i<4;i++) tile[ty+8*i][tx] = in[(size_t)(r0+ty+8*i)*Cc + c0+tx];
  __syncthreads();
  #pragma unroll
  for (int i=0;i<4;i++) out[(size_t)(c0+ty+8*i)*R + r0+tx] = tile[tx][ty+8*i];
}

__global__ void cvt_bf16x4(const float* __restrict__ in, u16* __restrict__ out, int n4)
{
  int i = blockIdx.x*256 + threadIdx.x;
  if (i < n4){
    float4 v = ((const float4*)in)[i];
    ushort4 p; p.x=f2bf(v.x); p.y=f2bf(v.y); p.z=f2bf(v.z); p.w=f2bf(v.w);
    ((ushort4*)out)[i] = p;
  }
}

__global__ void atab_k(const float* __restrict__ A_log, float* __restrict__ A_tab)
{
  int i = blockIdx.x*256 + threadIdx.x;
  if (i < 512*16) A_tab[i] = -__expf(A_log[i]);
}

// out_delta = sigmoid(log_gamma) * delta_W  (split-K delta GEMM atomicAdds on top)
__global__ void delta_init(const float* __restrict__ dW, const float* __restrict__ lg, float* __restrict__ out)
{
  int i = blockIdx.x*256 + threadIdx.x;   // over 2560*1024/4
  float g = sigm_(lg[0]);
  float4 v = ((const float4*)dW)[i];
  float4 r; r.x=g*v.x; r.y=g*v.y; r.z=g*v.z; r.w=g*v.w;
  ((float4*)out)[i] = r;
}

// RMSNorm over rows of 1024 f32 -> bf16
__global__ __launch_bounds__(256) void rmsnorm_k(const float* __restrict__ x, const float* __restrict__ w, u16* __restrict__ out)
{
  const int row = blockIdx.x, tid = threadIdx.x;
  float4 v = ((const float4*)(x + (size_t)row*1024))[tid];
  float s = v.x*v.x + v.y*v.y + v.z*v.z + v.w*v.w;
  #pragma unroll
  for (int o=32;o>0;o>>=1) s += __shfl_down(s, o);
  __shared__ float red[4];
  const int wave = tid>>6, lane = tid&63;
  if (lane==0) red[wave] = s;
  __syncthreads();
  float tot = red[0]+red[1]+red[2]+red[3];
  float sc = rsqrtf(tot*(1.f/1024.f) + 1e-6f);
  float4 wv = ((const float4*)w)[tid];
  ushort4 p; p.x=f2bf(v.x*sc*wv.x); p.y=f2bf(v.y*sc*wv.y); p.z=f2bf(v.z*sc*wv.z); p.w=f2bf(v.w*sc*wv.w);
  ((ushort4*)(out + (size_t)row*1024))[tid] = p;
}

// depthwise causal conv (K=4) + silu gate -> mixed cols 0..511
__global__ __launch_bounds__(256) void conv_k(const u16* __restrict__ P1, const float* __restrict__ kw, u16* __restrict__ mixed)
{
  const int idx = blockIdx.x*256 + threadIdx.x;   // B*C*512
  const int c = idx & 511;
  const int t = (idx>>9) & 2047;
  const int b = idx >> 20;
  const size_t rowb = (size_t)b*2048;
  float g = bf2f(P1[(rowb+t)*1024 + c]);
  float acc = 0.f;
  #pragma unroll
  for (int k=0;k<4;k++){
    int tt = t-3+k;
    if (tt>=0) acc += bf2f(P1[(rowb+tt)*1024 + 512 + c]) * kw[k*512+c];
  }
  mixed[(rowb+t)*1024 + c] = f2bf(silu_(g)*acc);
}

// chunked selective scan: 16 chunks of 128
__global__ __launch_bounds__(256) void scan_p1(const float* __restrict__ dt, const u16* __restrict__ P2,
                                               const float* __restrict__ BCs, const float* __restrict__ A_tab,
                                               float* __restrict__ hend, float* __restrict__ aprod)
{
  const int d = blockIdx.x*256 + threadIdx.x;
  const int ch = blockIdx.y, b = blockIdx.z;
  float Ar[16], h[16], ap[16];
  #pragma unroll
  for (int s=0;s<16;s++){ Ar[s] = A_tab[d*16+s]; h[s]=0.f; ap[s]=1.f; }
  const int t0 = ch*128;
  for (int t=0;t<128;t++){
    size_t row = (size_t)b*2048 + t0 + t;
    float dtv = dt[row*512 + d];
    float u = bf2f(P2[row*1024 + d]);
    float du = dtv*u;
    const float* bs = BCs + row*32;
    #pragma unroll
    for (int s=0;s<16;s++){
      float dA = __expf(dtv*Ar[s]);
      h[s] = dA*h[s] + du*bs[s];
      ap[s] *= dA;
    }
  }
  size_t o = ((size_t)((b*512+d)*16 + ch))*16;
  #pragma unroll
  for (int s=0;s<16;s++){ hend[o+s]=h[s]; aprod[o+s]=ap[s]; }
}

__global__ __launch_bounds__(256) void scan_p2(const float* __restrict__ hend, const float* __restrict__ aprod,
                                               float* __restrict__ hin)
{
  const int g = blockIdx.x*256 + threadIdx.x;   // 32768 = (b*512+d)*16+s
  const int s = g & 15, bd = g >> 4;
  float h = 0.f;
  for (int ch=0; ch<16; ch++){
    size_t o = ((size_t)(bd*16+ch))*16 + s;
    hin[o] = h;
    h = aprod[o]*h + hend[o];
  }
}

__global__ __launch_bounds__(256) void scan_p3(const float* __restrict__ dt, const u16* __restrict__ P2,
                                               const float* __restrict__ BCs, const float* __restrict__ A_tab,
                                               const float* __restrict__ hin, const float* __restrict__ Dp,
                                               u16* __restrict__ mixed)
{
  const int d = blockIdx.x*256 + threadIdx.x;
  const int ch = blockIdx.y, b = blockIdx.z;
  float Ar[16], h[16];
  size_t o = ((size_t)((b*512+d)*16 + ch))*16;
  #pragma unroll
  for (int s=0;s<16;s++){ Ar[s] = A_tab[d*16+s]; h[s] = hin[o+s]; }
  const float Dd = Dp[d];
  const int t0 = ch*128;
  for (int t=0;t<128;t++){
    size_t row = (size_t)b*2048 + t0 + t;
    float dtv = dt[row*512 + d];
    float u = bf2f(P2[row*1024 + d]);
    float zv = bf2f(P2[row*1024 + 512 + d]);
    float du = dtv*u;
    const float* bs = BCs + row*32;
    const float* cs = bs + 16;
    float y = 0.f;
    #pragma unroll
    for (int s=0;s<16;s++){
      float dA = __expf(dtv*Ar[s]);
      h[s] = dA*h[s] + du*bs[s];
      y += h[s]*cs[s];
    }
    float outv = (y + Dd*u)*silu_(zv);
    mixed[row*1024 + 512 + d] = f2bf(outv);
  }
}

extern "C" void kernel_launch(void* const* d_in, const int* in_sizes, int n_in,
                              void* d_out, int out_size, void* d_ws, size_t ws_size,
                              hipStream_t stream)
{
  const float* x          = (const float*)d_in[0];
  const float* velocity   = (const float*)d_in[1];
  const float* v_hat      = (const float*)d_in[2];
  const float* delta_W    = (const float*)d_in[3];
  const float* pre_norm_w = (const float*)d_in[4];
  const float* ffn_norm_w = (const float*)d_in[5];
  const float* conv_in_w  = (const float*)d_in[6];
  const float* conv_kw    = (const float*)d_in[7];
  const float* ssm_in_w   = (const float*)d_in[8];
  const float* ssm_dt_w   = (const float*)d_in[9];
  const float* ssm_dt_b   = (const float*)d_in[10];
  const float* ssm_A_log  = (const float*)d_in[11];
  const float* ssm_B_w    = (const float*)d_in[12];
  const float* ssm_C_w    = (const float*)d_in[13];
  const float* ssm_D      = (const float*)d_in[14];
  const float* out_proj_w = (const float*)d_in[15];
  const float* log_beta   = (const float*)d_in[16];
  const float* gate_up_w  = (const float*)d_in[17];
  const float* ffn_down_w = (const float*)d_in[18];
  const float* ffn_tgt_w  = (const float*)d_in[19];
  const float* log_gamma  = (const float*)d_in[20];
  const float* log_eta    = (const float*)d_in[21];

  float* out_x     = (float*)d_out;
  float* out_vel   = out_x + (size_t)ROWS_*D_;
  float* out_delta = out_vel + (size_t)ROWS_*D_;

  char* wsp = (char*)d_ws;
  size_t off = 0;
  auto alloc = [&](size_t bytes)->char*{ char* p = wsp + off; off += (bytes + 255) & ~(size_t)255; return p; };

  u16* Wti        = (u16*)alloc((size_t)2688*1024*2);   // combined in-proj weight^T
  u16* out_proj_t = (u16*)alloc((size_t)1024*1024*2);
  u16* gate_up_t  = (u16*)alloc((size_t)5120*1024*2);   // interleaved
  u16* target_t   = (u16*)alloc((size_t)2560*1024*2);
  u16* weff_t     = (u16*)alloc((size_t)1024*2560*2);
  float* A_tab    = (float*)alloc((size_t)512*16*4);
  u16* xn         = (u16*)alloc((size_t)ROWS_*1024*2);
  u16* P1         = (u16*)alloc((size_t)ROWS_*1024*2);
  u16* P2         = (u16*)alloc((size_t)ROWS_*1024*2);
  float* dtbuf    = (float*)alloc((size_t)ROWS_*512*4);
  float* BCs      = (float*)alloc((size_t)ROWS_*32*4);
  float* hend     = (float*)alloc((size_t)4*512*16*16*4);
  float* aprod    = (float*)alloc((size_t)4*512*16*16*4);
  float* hin      = (float*)alloc((size_t)4*512*16*16*4);
  u16* mixed      = (u16*)alloc((size_t)ROWS_*1024*2);
  u16* ffn_in     = (u16*)alloc((size_t)ROWS_*1024*2);
  u16* zbuf       = (u16*)alloc((size_t)ROWS_*2560*2);
  u16* T1t        = (u16*)alloc((size_t)2560*ROWS_*2);
  u16* ffn_inT    = xn;   // reuse: xn dead after in-proj GEMM
  u16* vhat_bf    = P1;   // reuse: P1 dead after conv_k

  dim3 tb(32,8);
  // weight prep
  transpose_cvt<<<dim3(32,32),  tb, 0, stream>>>(conv_in_w,  Wti,                    1024, 1024);
  transpose_cvt<<<dim3(32,32),  tb, 0, stream>>>(ssm_in_w,   Wti + (size_t)1024*1024,1024, 1024);
  transpose_cvt<<<dim3(16,32),  tb, 0, stream>>>(ssm_dt_w,   Wti + (size_t)2048*1024,1024, 512);
  bcw_cvt<<<512, 256, 0, stream>>>(ssm_B_w, ssm_C_w, Wti + (size_t)2560*1024);
  transpose_cvt<<<dim3(32,32),  tb, 0, stream>>>(out_proj_w, out_proj_t, 1024, 1024);
  transpose_cvt_gu<<<dim3(160,32), tb, 0, stream>>>(gate_up_w, gate_up_t);
  transpose_cvt<<<dim3(80,32),  tb, 0, stream>>>(ffn_tgt_w,  target_t,  1024, 2560);
  weff_transpose<<<dim3(32,80), tb, 0, stream>>>(ffn_down_w, delta_W, weff_t);
  atab_k<<<32, 256, 0, stream>>>(ssm_A_log, A_tab);
  delta_init<<<2560, 256, 0, stream>>>(delta_W, log_gamma, out_delta);

  // pre-norm + fused input projections (conv_in | ssm_in | dt | B/C)
  rmsnorm_k<<<ROWS_, 256, 0, stream>>>(x, pre_norm_w, xn);
  gemm128<EPI_INPROJ><<<dim3(21,64), 256, 0, stream>>>(xn, Wti, ROWS_,2688,1024,1024,
      dtbuf, BCs, ssm_dt_b, nullptr, nullptr, P1, P2);

  // conv branch + ssm branch -> mixed
  conv_k<<<16384, 256, 0, stream>>>(P1, conv_kw, mixed);
  scan_p1<<<dim3(2,16,4), 256, 0, stream>>>(dtbuf, P2, BCs, A_tab, hend, aprod);
  scan_p2<<<128, 256, 0, stream>>>(hend, aprod, hin);
  scan_p3<<<dim3(2,16,4), 256, 0, stream>>>(dtbuf, P2, BCs, A_tab, hin, ssm_D, mixed);

  // out_proj + momentum residual -> velocity, x_new
  gemm128<EPI_MOM><<<dim3(8,64), 256, 0, stream>>>(mixed, out_proj_t, ROWS_,1024,1024,1024,
      out_vel, out_x, velocity, x, log_beta, nullptr, nullptr);

  // FFN
  rmsnorm_k<<<ROWS_, 256, 0, stream>>>(out_x, ffn_norm_w, ffn_in);
  transpose_bf16<<<dim3(32,256), tb, 0, stream>>>(ffn_in, ffn_inT, ROWS_, 1024);
  cvt_bf16x4<<<8192, 256, 0, stream>>>(v_hat, vhat_bf, ROWS_*1024/4);

  // fused gate/up (interleaved) -> z = silu(gate)*up
  gemm128<EPI_SWIGLU><<<dim3(40,64), 256, 0, stream>>>(ffn_in, gate_up_t, ROWS_,5120,1024,1024,
      nullptr,nullptr,nullptr,nullptr,nullptr, zbuf, nullptr);
  // v_hat_proj^T
  gemm128<EPI_TRANS><<<dim3(20,64), 256, 0, stream>>>(vhat_bf, target_t, ROWS_,2560,1024,1024,
      nullptr,nullptr,nullptr,nullptr,nullptr, T1t, nullptr);

  // down-proj (fused fast-weight), split-K x2, atomic into final x
  gemm128<EPI_ATOMX><<<dim3(8,64,2), 256, 0, stream>>>(zbuf, weff_t, ROWS_,1024,2560,1280,
      out_x,nullptr,nullptr,nullptr,nullptr, nullptr,nullptr);

  // delta_W update: split-K x8, atomic into out_delta (pre-initialized g*delta_W)
  gemm128<EPI_ATOMD><<<dim3(8,20,8), 256, 0, stream>>>(T1t, ffn_inT, 2560,1024,ROWS_,1024,
      out_delta,nullptr,nullptr,nullptr, log_eta, nullptr,nullptr);
}

// Round 3
// 882.298 us; speedup vs baseline: 1.2933x; 1.1102x over previous
//
#include <hip/hip_runtime.h>
#include <stdint.h>
#include <stddef.h>

#define B_ 4
#define C_ 2048
#define D_ 1024
#define FFN_ 2560
#define ROWS_ 8192   // B_*C_

typedef unsigned short u16;
typedef short bf16x8 __attribute__((ext_vector_type(8)));
typedef float f32x4 __attribute__((ext_vector_type(4)));

__device__ __forceinline__ float bf2f(u16 x){ union { unsigned u; float f; } v; v.u = ((unsigned)x)<<16; return v.f; }
__device__ __forceinline__ u16 f2bf(float f){ union { float f; unsigned u; } v; v.f = f; unsigned r = v.u + 0x7fffu + ((v.u>>16)&1u); return (u16)(r>>16); }
__device__ __forceinline__ float sigm_(float x){ return 1.f/(1.f+__expf(-x)); }
__device__ __forceinline__ float silu_(float x){ return x/(1.f+__expf(-x)); }
__device__ __forceinline__ float softplus_(float x){ return (x>15.f)? x : log1pf(__expf(x)); }

__device__ __forceinline__ void async16(u16* lds_base, const u16* g){
  __builtin_amdgcn_global_load_lds((const __attribute__((address_space(1))) unsigned int*)g,
                                   (__attribute__((address_space(3))) unsigned int*)lds_base,
                                   16, 0, 0);
}

// ---------------- GEMM: C(MxN) = A(MxK,row-major bf16) * Bt(NxK,row-major bf16)^T
#define EPI_INPROJ 0
#define EPI_MOM    1
#define EPI_SWIGLU 2
#define EPI_TRANS  3
#define EPI_ATOMX  4
#define EPI_ATOMD  5

template<int EPI>
__global__ __launch_bounds__(256)
void gemm128(const u16* __restrict__ A, const u16* __restrict__ Bt,
             int M, int N, int K, int ksplit,
             float* __restrict__ f0, float* __restrict__ f1,
             const float* __restrict__ c0, const float* __restrict__ c1, const float* __restrict__ c2,
             u16* __restrict__ h0, u16* __restrict__ h1)
{
  __shared__ u16 smem[8192];          // As = smem[0:4096], Bs = smem[4096:8192]
  u16* As = smem;
  u16* Bs = smem + 4096;
  const int tid  = threadIdx.x;
  const int wave = tid>>6, lane = tid&63;
  const int bm = blockIdx.y*128, bn = blockIdx.x*128;
  const int srow = wave*32 + (lane>>2);
  const int scol = (lane&3)*8;
  const u16* aG0 = A  + (size_t)(bm + srow)*K + scol;
  const u16* aG1 = aG0 + (size_t)16*K;
  const u16* bG0 = Bt + (size_t)(bn + srow)*K + scol;
  const u16* bG1 = bG0 + (size_t)16*K;
  u16* aL0 = As + (wave*2+0)*512;
  u16* aL1 = As + (wave*2+1)*512;
  u16* bL0 = Bs + (wave*2+0)*512;
  u16* bL1 = Bs + (wave*2+1)*512;
  const int wr = wave>>1, wc = wave&1;
  const int mrow = lane&15, quad = lane>>4;

  f32x4 acc[4][4];
  #pragma unroll
  for (int i=0;i<4;i++)
    #pragma unroll
    for (int j=0;j<4;j++) acc[i][j] = (f32x4){0.f,0.f,0.f,0.f};

  const int kbeg = blockIdx.z * ksplit;
  const int kend = kbeg + ksplit;
  for (int k0=kbeg; k0<kend; k0+=32){
    __syncthreads();
    async16(aL0, aG0 + k0);
    async16(aL1, aG1 + k0);
    async16(bL0, bG0 + k0);
    async16(bL1, bG1 + k0);
    __syncthreads();
    bf16x8 af[4], bfv[4];
    #pragma unroll
    for (int i=0;i<4;i++) af[i]  = *(const bf16x8*)(As + (wr*64+i*16+mrow)*32 + quad*8);
    #pragma unroll
    for (int j=0;j<4;j++) bfv[j] = *(const bf16x8*)(Bs + (wc*64+j*16+mrow)*32 + quad*8);
    #pragma unroll
    for (int i=0;i<4;i++)
      #pragma unroll
      for (int j=0;j<4;j++)
        acc[i][j] = __builtin_amdgcn_mfma_f32_16x16x32_bf16(af[i], bfv[j], acc[i][j], 0,0,0);
  }

  if constexpr (EPI == EPI_TRANS){
    // LDS-staged transposed write: 4 passes of 32 columns; coalesced global stores
    __syncthreads();
    #pragma unroll
    for (int h=0; h<4; h++){
      const int hw = h>>1, j0 = (h&1)*2;
      if (wc == hw){
        #pragma unroll
        for (int i=0;i<4;i++){
          const int rbase = wr*64 + i*16 + quad*4;
          #pragma unroll
          for (int jj=0;jj<2;jj++){
            const int j = j0+jj;
            const int cl = jj*16 + mrow;
            f32x4 v = acc[i][j];
            #pragma unroll
            for (int t=0;t<4;t++) smem[cl*132 + rbase + t] = f2bf(v[t]);
          }
        }
      }
      __syncthreads();
      {
        const int cl2 = tid>>3, m0 = (tid&7)*16;
        const int col = bn + h*32 + cl2;
        const ushort4* s4 = (const ushort4*)(smem + cl2*132 + m0);
        ushort4* d4 = (ushort4*)(h0 + (size_t)col*M + bm + m0);
        #pragma unroll
        for (int q=0;q<4;q++) d4[q] = s4[q];
      }
      __syncthreads();
    }
  } else {
    #pragma unroll
    for (int i=0;i<4;i++){
      const int row0 = bm + wr*64 + i*16 + quad*4;
      if constexpr (EPI == EPI_SWIGLU){
        // 16-granular interleave: j even = gate block, j odd = up block (same lane pairs)
        #pragma unroll
        for (int jp=0;jp<4;jp+=2){
          f32x4 g = acc[i][jp];
          f32x4 u = acc[i][jp+1];
          const int o = (((bn + wc*64 + jp*16)>>5)<<4) + mrow;   // [0,2560)
          #pragma unroll
          for (int t=0;t<4;t++) h0[(size_t)(row0+t)*2560 + o] = f2bf(silu_(g[t])*u[t]);
        }
      } else {
        #pragma unroll
        for (int j=0;j<4;j++){
          const int col = bn + wc*64 + j*16 + mrow;
          f32x4 v = acc[i][j];
          if constexpr (EPI == EPI_INPROJ){
            if (col < 1024){
              #pragma unroll
              for (int t=0;t<4;t++) h0[(size_t)(row0+t)*1024 + col] = f2bf(v[t]);
            } else if (col < 2048){
              #pragma unroll
              for (int t=0;t<4;t++) h1[(size_t)(row0+t)*1024 + (col-1024)] = f2bf(v[t]);
            } else if (col < 2560){
              const float b = c0[col-2048];
              #pragma unroll
              for (int t=0;t<4;t++) f0[(size_t)(row0+t)*512 + (col-2048)] = softplus_(v[t]+b);
            } else {
              const int cl = col - 2560;
              if (cl < 32){
                #pragma unroll
                for (int t=0;t<4;t++) f1[(size_t)(row0+t)*32 + cl] = v[t];
              }
            }
          } else if constexpr (EPI == EPI_MOM){
            const float beta = sigm_(c2[0]);
            #pragma unroll
            for (int t=0;t<4;t++){
              size_t idx = (size_t)(row0+t)*N + col;
              float vel = beta*c0[idx] + v[t];
              f0[idx] = vel;
              f1[idx] = c1[idx] + vel;
            }
          } else if constexpr (EPI == EPI_ATOMX){
            #pragma unroll
            for (int t=0;t<4;t++) atomicAdd(&f0[(size_t)(row0+t)*N + col], v[t]);
          } else if constexpr (EPI == EPI_ATOMD){
            const float e = softplus_(c2[0])*0.25f;
            #pragma unroll
            for (int t=0;t<4;t++) atomicAdd(&f0[(size_t)(row0+t)*N + col], e*v[t]);
          }
        }
      }
    }
  }
}

// ---------------- combined weight transposes (z-indexed)
__global__ void prep_transposes(const float* __restrict__ conv_in_w, const float* __restrict__ ssm_in_w,
                                const float* __restrict__ ssm_dt_w, const float* __restrict__ out_proj_w,
                                const float* __restrict__ ffn_tgt_w, const float* __restrict__ gate_up_w,
                                u16* __restrict__ Wti, u16* __restrict__ out_proj_t,
                                u16* __restrict__ target_t, u16* __restrict__ gate_up_t)
{
  const int z = blockIdx.z;
  const float* W; u16* Wt; int N; bool gu = false;
  switch(z){
    case 0: W=conv_in_w;  Wt=Wti;                       N=1024; break;
    case 1: W=ssm_in_w;   Wt=Wti + (size_t)1024*1024;   N=1024; break;
    case 2: W=ssm_dt_w;   Wt=Wti + (size_t)2048*1024;   N=512;  break;
    case 3: W=out_proj_w; Wt=out_proj_t;                N=1024; break;
    case 4: W=ffn_tgt_w;  Wt=target_t;                  N=2560; break;
    default: W=gate_up_w; Wt=gate_up_t;                 N=5120; gu=true; break;
  }
  const int c0 = blockIdx.x*32, r0 = blockIdx.y*32;
  if (c0 >= N) return;
  __shared__ float tile[32][33];
  const int tx = threadIdx.x, ty = threadIdx.y;
  #pragma unroll
  for (int i=0;i<4;i++) tile[ty+8*i][tx] = W[(size_t)(r0+ty+8*i)*N + c0+tx];
  __syncthreads();
  #pragma unroll
  for (int i=0;i<4;i++){
    const int c = c0+ty+8*i;
    int n;
    if (gu){
      if (c < 2560) n = ((c>>4)<<5) | (c&15);
      else { int o = c-2560; n = ((o>>4)<<5) | 16 | (o&15); }
    } else n = c;
    Wt[(size_t)n*1024 + r0+tx] = f2bf(tile[tx][ty+8*i]);
  }
}

// W_eff = ffn_down + delta_W, transposed: (2560x1024) -> (1024x2560) bf16
__global__ void weff_transpose(const float* __restrict__ Wa, const float* __restrict__ Wb, u16* __restrict__ Wt)
{
  __shared__ float tile[32][33];
  const int tx = threadIdx.x, ty = threadIdx.y;
  const int c0 = blockIdx.x*32, r0 = blockIdx.y*32;
  #pragma unroll
  for (int i=0;i<4;i++){
    size_t idx = (size_t)(r0+ty+8*i)*1024 + c0+tx;
    tile[ty+8*i][tx] = Wa[idx] + Wb[idx];
  }
  __syncthreads();
  #pragma unroll
  for (int i=0;i<4;i++) Wt[(size_t)(c0+ty+8*i)*2560 + r0+tx] = f2bf(tile[tx][ty+8*i]);
}

// bf16 transpose (in: R x Cc -> out: Cc x R)
__global__ void transpose_bf16(const u16* __restrict__ in, u16* __restrict__ out, int R, int Cc)
{
  __shared__ u16 tile[32][33];
  const int tx = threadIdx.x, ty = threadIdx.y;
  const int c0 = blockIdx.x*32, r0 = blockIdx.y*32;
  #pragma unroll
  for (int i=0;i<4;i++) tile[ty+8*i][tx] = in[(size_t)(r0+ty+8*i)*Cc + c0+tx];
  __syncthreads();
  #pragma unroll
  for (int i=0;i<4;i++) out[(size_t)(c0+ty+8*i)*R + r0+tx] = tile[tx][ty+8*i];
}

__global__ void cvt_bf16x4(const float* __restrict__ in, u16* __restrict__ out, int n4)
{
  int i = blockIdx.x*256 + threadIdx.x;
  if (i < n4){
    float4 v = ((const float4*)in)[i];
    ushort4 p; p.x=f2bf(v.x); p.y=f2bf(v.y); p.z=f2bf(v.z); p.w=f2bf(v.w);
    ((ushort4*)out)[i] = p;
  }
}

// merged: delta_init (blocks [0,2560)) | B/C weight pack (blocks [2560,3072)) | A_tab (blocks [3072,3104))
__global__ void prep_small(const float* __restrict__ dW, const float* __restrict__ lg,
                           const float* __restrict__ Bw, const float* __restrict__ Cw,
                           const float* __restrict__ A_log,
                           float* __restrict__ out_delta, u16* __restrict__ bc_dst,
                           float* __restrict__ A_tab)
{
  const int blk = blockIdx.x, tid = threadIdx.x;
  if (blk < 2560){
    int i = blk*256 + tid;            // over 2560*1024/4 float4
    float g = sigm_(lg[0]);
    float4 v = ((const float4*)dW)[i];
    float4 r; r.x=g*v.x; r.y=g*v.y; r.z=g*v.z; r.w=g*v.w;
    ((float4*)out_delta)[i] = r;
  } else if (blk < 3072){
    int i = (blk-2560)*256 + tid;     // 128*1024
    int r = i >> 10, k = i & 1023;
    float v = 0.f;
    if (r < 16) v = Bw[k*16 + r];
    else if (r < 32) v = Cw[k*16 + (r-16)];
    bc_dst[(size_t)r*1024 + k] = f2bf(v);
  } else {
    int i = (blk-3072)*256 + tid;
    if (i < 512*16) A_tab[i] = -__expf(A_log[i]);
  }
}

// RMSNorm over rows of 1024 f32 -> bf16
__global__ __launch_bounds__(256) void rmsnorm_k(const float* __restrict__ x, const float* __restrict__ w, u16* __restrict__ out)
{
  const int row = blockIdx.x, tid = threadIdx.x;
  float4 v = ((const float4*)(x + (size_t)row*1024))[tid];
  float s = v.x*v.x + v.y*v.y + v.z*v.z + v.w*v.w;
  #pragma unroll
  for (int o=32;o>0;o>>=1) s += __shfl_down(s, o);
  __shared__ float red[4];
  const int wave = tid>>6, lane = tid&63;
  if (lane==0) red[wave] = s;
  __syncthreads();
  float tot = red[0]+red[1]+red[2]+red[3];
  float sc = rsqrtf(tot*(1.f/1024.f) + 1e-6f);
  float4 wv = ((const float4*)w)[tid];
  ushort4 p; p.x=f2bf(v.x*sc*wv.x); p.y=f2bf(v.y*sc*wv.y); p.z=f2bf(v.z*sc*wv.z); p.w=f2bf(v.w*sc*wv.w);
  ((ushort4*)(out + (size_t)row*1024))[tid] = p;
}

// depthwise causal conv (K=4) + silu gate -> mixed cols 0..511
__global__ __launch_bounds__(256) void conv_k(const u16* __restrict__ P1, const float* __restrict__ kw, u16* __restrict__ mixed)
{
  const int idx = blockIdx.x*256 + threadIdx.x;   // B*C*512
  const int c = idx & 511;
  const int t = (idx>>9) & 2047;
  const int b = idx >> 20;
  const size_t rowb = (size_t)b*2048;
  float g = bf2f(P1[(rowb+t)*1024 + c]);
  float acc = 0.f;
  #pragma unroll
  for (int k=0;k<4;k++){
    int tt = t-3+k;
    if (tt>=0) acc += bf2f(P1[(rowb+tt)*1024 + 512 + c]) * kw[k*512+c];
  }
  mixed[(rowb+t)*1024 + c] = f2bf(silu_(g)*acc);
}

// chunked selective scan: 64 chunks of 32
#define NCH_ 64
#define CHL_ 32
__global__ __launch_bounds__(256) void scan_p1(const float* __restrict__ dt, const u16* __restrict__ P2,
                                               const float* __restrict__ BCs, const float* __restrict__ A_tab,
                                               float* __restrict__ hend, float* __restrict__ aprod)
{
  const int d = blockIdx.x*256 + threadIdx.x;
  const int ch = blockIdx.y, b = blockIdx.z;
  float Ar[16], h[16], ap[16];
  #pragma unroll
  for (int s=0;s<16;s++){ Ar[s] = A_tab[d*16+s]; h[s]=0.f; ap[s]=1.f; }
  const int t0 = ch*CHL_;
  for (int t=0;t<CHL_;t++){
    size_t row = (size_t)b*2048 + t0 + t;
    float dtv = dt[row*512 + d];
    float u = bf2f(P2[row*1024 + d]);
    float du = dtv*u;
    const float* bs = BCs + row*32;
    #pragma unroll
    for (int s=0;s<16;s++){
      float dA = __expf(dtv*Ar[s]);
      h[s] = dA*h[s] + du*bs[s];
      ap[s] *= dA;
    }
  }
  size_t o = ((size_t)((b*512+d)*NCH_ + ch))*16;
  #pragma unroll
  for (int s=0;s<16;s++){ hend[o+s]=h[s]; aprod[o+s]=ap[s]; }
}

// sequential over chunks; rewrites hend in place with chunk-entry states
__global__ __launch_bounds__(256) void scan_p2(float* __restrict__ hend, const float* __restrict__ aprod)
{
  const int g = blockIdx.x*256 + threadIdx.x;   // 32768 = (b*512+d)*16+s
  const int s = g & 15, bd = g >> 4;
  float h = 0.f;
  for (int ch=0; ch<NCH_; ch++){
    size_t o = ((size_t)(bd*NCH_+ch))*16 + s;
    float he = hend[o], ap = aprod[o];
    hend[o] = h;                 // h at chunk entry
    h = ap*h + he;
  }
}

__global__ __launch_bounds__(256) void scan_p3(const float* __restrict__ dt, const u16* __restrict__ P2,
                                               const float* __restrict__ BCs, const float* __restrict__ A_tab,
                                               const float* __restrict__ hin, const float* __restrict__ Dp,
                                               u16* __restrict__ mixed)
{
  const int d = blockIdx.x*256 + threadIdx.x;
  const int ch = blockIdx.y, b = blockIdx.z;
  float Ar[16], h[16];
  size_t o = ((size_t)((b*512+d)*NCH_ + ch))*16;
  #pragma unroll
  for (int s=0;s<16;s++){ Ar[s] = A_tab[d*16+s]; h[s] = hin[o+s]; }
  const float Dd = Dp[d];
  const int t0 = ch*CHL_;
  for (int t=0;t<CHL_;t++){
    size_t row = (size_t)b*2048 + t0 + t;
    float dtv = dt[row*512 + d];
    float u = bf2f(P2[row*1024 + d]);
    float zv = bf2f(P2[row*1024 + 512 + d]);
    float du = dtv*u;
    const float* bs = BCs + row*32;
    const float* cs = bs + 16;
    float y = 0.f;
    #pragma unroll
    for (int s=0;s<16;s++){
      float dA = __expf(dtv*Ar[s]);
      h[s] = dA*h[s] + du*bs[s];
      y += h[s]*cs[s];
    }
    float outv = (y + Dd*u)*silu_(zv);
    mixed[row*1024 + 512 + d] = f2bf(outv);
  }
}

extern "C" void kernel_launch(void* const* d_in, const int* in_sizes, int n_in,
                              void* d_out, int out_size, void* d_ws, size_t ws_size,
                              hipStream_t stream)
{
  const float* x          = (const float*)d_in[0];
  const float* velocity   = (const float*)d_in[1];
  const float* v_hat      = (const float*)d_in[2];
  const float* delta_W    = (const float*)d_in[3];
  const float* pre_norm_w = (const float*)d_in[4];
  const float* ffn_norm_w = (const float*)d_in[5];
  const float* conv_in_w  = (const float*)d_in[6];
  const float* conv_kw    = (const float*)d_in[7];
  const float* ssm_in_w   = (const float*)d_in[8];
  const float* ssm_dt_w   = (const float*)d_in[9];
  const float* ssm_dt_b   = (const float*)d_in[10];
  const float* ssm_A_log  = (const float*)d_in[11];
  const float* ssm_B_w    = (const float*)d_in[12];
  const float* ssm_C_w    = (const float*)d_in[13];
  const float* ssm_D      = (const float*)d_in[14];
  const float* out_proj_w = (const float*)d_in[15];
  const float* log_beta   = (const float*)d_in[16];
  const float* gate_up_w  = (const float*)d_in[17];
  const float* ffn_down_w = (const float*)d_in[18];
  const float* ffn_tgt_w  = (const float*)d_in[19];
  const float* log_gamma  = (const float*)d_in[20];
  const float* log_eta    = (const float*)d_in[21];

  float* out_x     = (float*)d_out;
  float* out_vel   = out_x + (size_t)ROWS_*D_;
  float* out_delta = out_vel + (size_t)ROWS_*D_;

  char* wsp = (char*)d_ws;
  size_t off = 0;
  auto alloc = [&](size_t bytes)->char*{ char* p = wsp + off; off += (bytes + 255) & ~(size_t)255; return p; };

  u16* Wti        = (u16*)alloc((size_t)2688*1024*2);   // combined in-proj weight^T
  u16* out_proj_t = (u16*)alloc((size_t)1024*1024*2);
  u16* gate_up_t  = (u16*)alloc((size_t)5120*1024*2);   // 16-granular interleave
  u16* target_t   = (u16*)alloc((size_t)2560*1024*2);
  u16* weff_t     = (u16*)alloc((size_t)1024*2560*2);
  float* A_tab    = (float*)alloc((size_t)512*16*4);
  u16* xn         = (u16*)alloc((size_t)ROWS_*1024*2);
  u16* P1         = (u16*)alloc((size_t)ROWS_*1024*2);
  u16* P2         = (u16*)alloc((size_t)ROWS_*1024*2);
  float* dtbuf    = (float*)alloc((size_t)ROWS_*512*4);
  float* BCs      = (float*)alloc((size_t)ROWS_*32*4);
  float* hend     = (float*)alloc((size_t)4*512*NCH_*16*4);
  float* aprod    = (float*)alloc((size_t)4*512*NCH_*16*4);
  u16* mixed      = (u16*)alloc((size_t)ROWS_*1024*2);
  u16* ffn_in     = (u16*)alloc((size_t)ROWS_*1024*2);
  u16* zbuf       = (u16*)alloc((size_t)ROWS_*2560*2);
  u16* T1t        = (u16*)alloc((size_t)2560*ROWS_*2);
  u16* ffn_inT    = xn;   // reuse: xn dead after in-proj GEMM
  u16* vhat_bf    = P1;   // reuse: P1 dead after conv_k

  dim3 tb(32,8);
  // weight prep (one z-indexed dispatch for the 6 transposes)
  prep_transposes<<<dim3(160,32,6), tb, 0, stream>>>(conv_in_w, ssm_in_w, ssm_dt_w, out_proj_w,
      ffn_tgt_w, gate_up_w, Wti, out_proj_t, target_t, gate_up_t);
  weff_transpose<<<dim3(32,80), tb, 0, stream>>>(ffn_down_w, delta_W, weff_t);
  prep_small<<<3104, 256, 0, stream>>>(delta_W, log_gamma, ssm_B_w, ssm_C_w, ssm_A_log,
      out_delta, Wti + (size_t)2560*1024, A_tab);

  // pre-norm + fused input projections (conv_in | ssm_in | dt | B/C)
  rmsnorm_k<<<ROWS_, 256, 0, stream>>>(x, pre_norm_w, xn);
  gemm128<EPI_INPROJ><<<dim3(21,64), 256, 0, stream>>>(xn, Wti, ROWS_,2688,1024,1024,
      dtbuf, BCs, ssm_dt_b, nullptr, nullptr, P1, P2);

  // conv branch + ssm branch -> mixed
  conv_k<<<16384, 256, 0, stream>>>(P1, conv_kw, mixed);
  scan_p1<<<dim3(2,NCH_,4), 256, 0, stream>>>(dtbuf, P2, BCs, A_tab, hend, aprod);
  scan_p2<<<128, 256, 0, stream>>>(hend, aprod);
  scan_p3<<<dim3(2,NCH_,4), 256, 0, stream>>>(dtbuf, P2, BCs, A_tab, hend, ssm_D, mixed);

  // out_proj + momentum residual -> velocity, x_new
  gemm128<EPI_MOM><<<dim3(8,64), 256, 0, stream>>>(mixed, out_proj_t, ROWS_,1024,1024,1024,
      out_vel, out_x, velocity, x, log_beta, nullptr, nullptr);

  // FFN
  rmsnorm_k<<<ROWS_, 256, 0, stream>>>(out_x, ffn_norm_w, ffn_in);
  transpose_bf16<<<dim3(32,256), tb, 0, stream>>>(ffn_in, ffn_inT, ROWS_, 1024);
  cvt_bf16x4<<<8192, 256, 0, stream>>>(v_hat, vhat_bf, ROWS_*1024/4);

  // fused gate/up (16-granular interleave) -> z = silu(gate)*up
  gemm128<EPI_SWIGLU><<<dim3(40,64), 256, 0, stream>>>(ffn_in, gate_up_t, ROWS_,5120,1024,1024,
      nullptr,nullptr,nullptr,nullptr,nullptr, zbuf, nullptr);
  // v_hat_proj^T (LDS-staged transposed store)
  gemm128<EPI_TRANS><<<dim3(20,64), 256, 0, stream>>>(vhat_bf, target_t, ROWS_,2560,1024,1024,
      nullptr,nullptr,nullptr,nullptr,nullptr, T1t, nullptr);

  // down-proj (fused fast-weight), split-K x2, atomic into final x
  gemm128<EPI_ATOMX><<<dim3(8,64,2), 256, 0, stream>>>(zbuf, weff_t, ROWS_,1024,2560,1280,
      out_x,nullptr,nullptr,nullptr,nullptr, nullptr,nullptr);

  // delta_W update: split-K x8, atomic into out_delta (pre-initialized g*delta_W)
  gemm128<EPI_ATOMD><<<dim3(8,20,8), 256, 0, stream>>>(T1t, ffn_inT, 2560,1024,ROWS_,1024,
      out_delta,nullptr,nullptr,nullptr, log_eta, nullptr,nullptr);
}

// Round 4
// 877.482 us; speedup vs baseline: 1.3004x; 1.0055x over previous
//
#include <hip/hip_runtime.h>
#include <stdint.h>
#include <stddef.h>

#define B_ 4
#define C_ 2048
#define D_ 1024
#define FFN_ 2560
#define ROWS_ 8192   // B_*C_

typedef unsigned short u16;
typedef short bf16x8 __attribute__((ext_vector_type(8)));
typedef float f32x4 __attribute__((ext_vector_type(4)));

__device__ __forceinline__ float bf2f(u16 x){ union { unsigned u; float f; } v; v.u = ((unsigned)x)<<16; return v.f; }
__device__ __forceinline__ u16 f2bf(float f){ union { float f; unsigned u; } v; v.f = f; unsigned r = v.u + 0x7fffu + ((v.u>>16)&1u); return (u16)(r>>16); }
__device__ __forceinline__ float sigm_(float x){ return 1.f/(1.f+__expf(-x)); }
__device__ __forceinline__ float silu_(float x){ return x/(1.f+__expf(-x)); }
__device__ __forceinline__ float softplus_(float x){ return (x>15.f)? x : log1pf(__expf(x)); }

__device__ __forceinline__ void async16(u16* lds_base, const u16* g){
  __builtin_amdgcn_global_load_lds((const __attribute__((address_space(1))) unsigned int*)g,
                                   (__attribute__((address_space(3))) unsigned int*)lds_base,
                                   16, 0, 0);
}

// ---------------- GEMM: C(MxN) = A(MxK,row-major bf16) * Bt(NxK,row-major bf16)^T
// BK=64 K-loop; XOR-swizzled k-group LDS layout (slot s of row r holds k-group s^(r&7)).
#define EPI_INTRANS   0   // fused: x<21 -> input projections; x>=21 -> v_hat_proj^T
#define EPI_MOM       1
#define EPI_SWIGLU    2
#define EPI_DOWNDELTA 3   // fused: x<8 -> down-proj atomic; x>=8 -> delta update atomic

template<int EPI>
__global__ __launch_bounds__(256)
void gemm128(const u16* __restrict__ A, const u16* __restrict__ Bt,
             int M, int N, int K, int ksplit,
             float* __restrict__ f0, float* __restrict__ f1,
             const float* __restrict__ c0, const float* __restrict__ c1, const float* __restrict__ c2,
             u16* __restrict__ h0, u16* __restrict__ h1, u16* __restrict__ h2,
             const u16* __restrict__ a2, const u16* __restrict__ b2)
{
  __shared__ u16 smem[16384];          // As = [0:8192], Bs = [8192:16384]  (128x64 each)
  u16* As = smem;
  u16* Bs = smem + 8192;
  const int tid  = threadIdx.x;
  const int wave = tid>>6, lane = tid&63;

  int bx = blockIdx.x;
  bool alt = false;
  if constexpr (EPI == EPI_INTRANS){
    if (bx >= 21){ alt = true; bx -= 21; A = a2; Bt = b2; }
  }
  if constexpr (EPI == EPI_DOWNDELTA){
    if (bx >= 8){
      alt = true; bx -= 8;
      if ((int)blockIdx.y >= 20) return;   // delta: M=2560 -> 20 row-tiles
      A = a2; Bt = b2; K = 8192; ksplit = 2048;
    } else {
      if ((int)blockIdx.z >= 2) return;    // down-proj: only 2 K-splits
    }
  }
  const int bm = blockIdx.y*128, bn = bx*128;

  // staging: per wave 4 A-instrs + 4 B-instrs; instr q covers rows wave*32+q*8 .. +7
  const int lr8  = lane>>3;                  // row within 8-row chunk
  const int kswz = ((lane&7) ^ lr8)*8;       // swizzled k-group fetched by this lane
  const u16* aG[4]; const u16* bG[4]; u16* aL[4]; u16* bL[4];
  #pragma unroll
  for (int q=0;q<4;q++){
    const int r = wave*32 + q*8 + lr8;
    aG[q] = A  + (size_t)(bm + r)*K + kswz;
    bG[q] = Bt + (size_t)(bn + r)*K + kswz;
    aL[q] = As + (wave*32 + q*8)*64;
    bL[q] = Bs + (wave*32 + q*8)*64;
  }
  const int wr = wave>>1, wc = wave&1;
  const int mrow = lane&15, quad = lane>>4;
  const int swz8 = (mrow&7);

  f32x4 acc[4][4];
  #pragma unroll
  for (int i=0;i<4;i++)
    #pragma unroll
    for (int j=0;j<4;j++) acc[i][j] = (f32x4){0.f,0.f,0.f,0.f};

  const int kbeg = blockIdx.z * ksplit;
  const int kend = kbeg + ksplit;
  for (int k0=kbeg; k0<kend; k0+=64){
    __syncthreads();
    #pragma unroll
    for (int q=0;q<4;q++) async16(aL[q], aG[q] + k0);
    #pragma unroll
    for (int q=0;q<4;q++) async16(bL[q], bG[q] + k0);
    __syncthreads();
    #pragma unroll
    for (int kk=0; kk<64; kk+=32){
      bf16x8 af[4], bfv[4];
      const int gq = (kk>>3) + quad;
      const int pos = (gq ^ swz8)*8;
      #pragma unroll
      for (int i=0;i<4;i++) af[i]  = *(const bf16x8*)(As + (wr*64+i*16+mrow)*64 + pos);
      #pragma unroll
      for (int j=0;j<4;j++) bfv[j] = *(const bf16x8*)(Bs + (wc*64+j*16+mrow)*64 + pos);
      #pragma unroll
      for (int i=0;i<4;i++)
        #pragma unroll
        for (int j=0;j<4;j++)
          acc[i][j] = __builtin_amdgcn_mfma_f32_16x16x32_bf16(af[i], bfv[j], acc[i][j], 0,0,0);
    }
  }

  if constexpr (EPI == EPI_INTRANS){
    if (alt){
      // v_hat_proj^T: LDS-staged transposed write, coalesced global stores (cols of T1t, stride M=8192)
      __syncthreads();
      #pragma unroll
      for (int h=0; h<4; h++){
        const int hw = h>>1, j0 = (h&1)*2;
        if (wc == hw){
          #pragma unroll
          for (int i=0;i<4;i++){
            const int rbase = wr*64 + i*16 + quad*4;
            #pragma unroll
            for (int jj=0;jj<2;jj++){
              const int j = j0+jj;
              const int cl = jj*16 + mrow;
              f32x4 v = acc[i][j];
              #pragma unroll
              for (int t=0;t<4;t++) smem[cl*132 + rbase + t] = f2bf(v[t]);
            }
          }
        }
        __syncthreads();
        {
          const int cl2 = tid>>3, m0 = (tid&7)*16;
          const int col = bn + h*32 + cl2;
          const ushort4* s4 = (const ushort4*)(smem + cl2*132 + m0);
          ushort4* d4 = (ushort4*)(h2 + (size_t)col*8192 + bm + m0);
          #pragma unroll
          for (int q=0;q<4;q++) d4[q] = s4[q];
        }
        __syncthreads();
      }
    } else {
      // input projections: N=2688 = [P1 1024 | P2 1024 | dt 512 | BC 32 (+96 pad)]
      #pragma unroll
      for (int i=0;i<4;i++){
        const int row0 = bm + wr*64 + i*16 + quad*4;
        #pragma unroll
        for (int j=0;j<4;j++){
          const int col = bn + wc*64 + j*16 + mrow;
          f32x4 v = acc[i][j];
          if (col < 1024){
            #pragma unroll
            for (int t=0;t<4;t++) h0[(size_t)(row0+t)*1024 + col] = f2bf(v[t]);
          } else if (col < 2048){
            #pragma unroll
            for (int t=0;t<4;t++) h1[(size_t)(row0+t)*1024 + (col-1024)] = f2bf(v[t]);
          } else if (col < 2560){
            const float b = c0[col-2048];
            #pragma unroll
            for (int t=0;t<4;t++) f0[(size_t)(row0+t)*512 + (col-2048)] = softplus_(v[t]+b);
          } else {
            const int cl = col - 2560;
            if (cl < 32){
              #pragma unroll
              for (int t=0;t<4;t++) f1[(size_t)(row0+t)*32 + cl] = v[t];
            }
          }
        }
      }
    }
  } else if constexpr (EPI == EPI_MOM){
    const float beta = sigm_(c2[0]);
    #pragma unroll
    for (int i=0;i<4;i++){
      const int row0 = bm + wr*64 + i*16 + quad*4;
      #pragma unroll
      for (int j=0;j<4;j++){
        const int col = bn + wc*64 + j*16 + mrow;
        f32x4 v = acc[i][j];
        #pragma unroll
        for (int t=0;t<4;t++){
          size_t idx = (size_t)(row0+t)*1024 + col;
          float vel = beta*c0[idx] + v[t];
          f0[idx] = vel;
          f1[idx] = c1[idx] + vel;
        }
      }
    }
  } else if constexpr (EPI == EPI_SWIGLU){
    #pragma unroll
    for (int i=0;i<4;i++){
      const int row0 = bm + wr*64 + i*16 + quad*4;
      #pragma unroll
      for (int jp=0;jp<4;jp+=2){
        f32x4 g = acc[i][jp];
        f32x4 u = acc[i][jp+1];
        const int o = (((bn + wc*64 + jp*16)>>5)<<4) + mrow;   // [0,2560)
        #pragma unroll
        for (int t=0;t<4;t++) h0[(size_t)(row0+t)*2560 + o] = f2bf(silu_(g[t])*u[t]);
      }
    }
  } else if constexpr (EPI == EPI_DOWNDELTA){
    #pragma unroll
    for (int i=0;i<4;i++){
      const int row0 = bm + wr*64 + i*16 + quad*4;
      #pragma unroll
      for (int j=0;j<4;j++){
        const int col = bn + wc*64 + j*16 + mrow;
        f32x4 v = acc[i][j];
        if (!alt){
          #pragma unroll
          for (int t=0;t<4;t++) atomicAdd(&f0[(size_t)(row0+t)*1024 + col], v[t]);
        } else {
          const float e = softplus_(c2[0])*0.25f;
          #pragma unroll
          for (int t=0;t<4;t++) atomicAdd(&f1[(size_t)(row0+t)*1024 + col], e*v[t]);
        }
      }
    }
  }
}

// ---------------- combined weight transposes (z-indexed)
__global__ void prep_transposes(const float* __restrict__ conv_in_w, const float* __restrict__ ssm_in_w,
                                const float* __restrict__ ssm_dt_w, const float* __restrict__ out_proj_w,
                                const float* __restrict__ ffn_tgt_w, const float* __restrict__ gate_up_w,
                                u16* __restrict__ Wti, u16* __restrict__ out_proj_t,
                                u16* __restrict__ target_t, u16* __restrict__ gate_up_t)
{
  const int z = blockIdx.z;
  const float* W; u16* Wt; int N; bool gu = false;
  switch(z){
    case 0: W=conv_in_w;  Wt=Wti;                       N=1024; break;
    case 1: W=ssm_in_w;   Wt=Wti + (size_t)1024*1024;   N=1024; break;
    case 2: W=ssm_dt_w;   Wt=Wti + (size_t)2048*1024;   N=512;  break;
    case 3: W=out_proj_w; Wt=out_proj_t;                N=1024; break;
    case 4: W=ffn_tgt_w;  Wt=target_t;                  N=2560; break;
    default: W=gate_up_w; Wt=gate_up_t;                 N=5120; gu=true; break;
  }
  const int c0 = blockIdx.x*32, r0 = blockIdx.y*32;
  if (c0 >= N) return;
  __shared__ float tile[32][33];
  const int tx = threadIdx.x, ty = threadIdx.y;
  #pragma unroll
  for (int i=0;i<4;i++) tile[ty+8*i][tx] = W[(size_t)(r0+ty+8*i)*N + c0+tx];
  __syncthreads();
  #pragma unroll
  for (int i=0;i<4;i++){
    const int c = c0+ty+8*i;
    int n;
    if (gu){
      if (c < 2560) n = ((c>>4)<<5) | (c&15);
      else { int o = c-2560; n = ((o>>4)<<5) | 16 | (o&15); }
    } else n = c;
    Wt[(size_t)n*1024 + r0+tx] = f2bf(tile[tx][ty+8*i]);
  }
}

// W_eff = ffn_down + delta_W, transposed: (2560x1024) -> (1024x2560) bf16
__global__ void weff_transpose(const float* __restrict__ Wa, const float* __restrict__ Wb, u16* __restrict__ Wt)
{
  __shared__ float tile[32][33];
  const int tx = threadIdx.x, ty = threadIdx.y;
  const int c0 = blockIdx.x*32, r0 = blockIdx.y*32;
  #pragma unroll
  for (int i=0;i<4;i++){
    size_t idx = (size_t)(r0+ty+8*i)*1024 + c0+tx;
    tile[ty+8*i][tx] = Wa[idx] + Wb[idx];
  }
  __syncthreads();
  #pragma unroll
  for (int i=0;i<4;i++) Wt[(size_t)(c0+ty+8*i)*2560 + r0+tx] = f2bf(tile[tx][ty+8*i]);
}

// bf16 transpose (in: R x Cc -> out: Cc x R)
__global__ void transpose_bf16(const u16* __restrict__ in, u16* __restrict__ out, int R, int Cc)
{
  __shared__ u16 tile[32][33];
  const int tx = threadIdx.x, ty = threadIdx.y;
  const int c0 = blockIdx.x*32, r0 = blockIdx.y*32;
  #pragma unroll
  for (int i=0;i<4;i++) tile[ty+8*i][tx] = in[(size_t)(r0+ty+8*i)*Cc + c0+tx];
  __syncthreads();
  #pragma unroll
  for (int i=0;i<4;i++) out[(size_t)(c0+ty+8*i)*R + r0+tx] = tile[tx][ty+8*i];
}

__global__ void cvt_bf16x4(const float* __restrict__ in, u16* __restrict__ out, int n4)
{
  int i = blockIdx.x*256 + threadIdx.x;
  if (i < n4){
    float4 v = ((const float4*)in)[i];
    ushort4 p; p.x=f2bf(v.x); p.y=f2bf(v.y); p.z=f2bf(v.z); p.w=f2bf(v.w);
    ((ushort4*)out)[i] = p;
  }
}

// merged: delta_init (blocks [0,2560)) | B/C weight pack (blocks [2560,3072)) | A_tab (blocks [3072,3104))
__global__ void prep_small(const float* __restrict__ dW, const float* __restrict__ lg,
                           const float* __restrict__ Bw, const float* __restrict__ Cw,
                           const float* __restrict__ A_log,
                           float* __restrict__ out_delta, u16* __restrict__ bc_dst,
                           float* __restrict__ A_tab)
{
  const int blk = blockIdx.x, tid = threadIdx.x;
  if (blk < 2560){
    int i = blk*256 + tid;            // over 2560*1024/4 float4
    float g = sigm_(lg[0]);
    float4 v = ((const float4*)dW)[i];
    float4 r; r.x=g*v.x; r.y=g*v.y; r.z=g*v.z; r.w=g*v.w;
    ((float4*)out_delta)[i] = r;
  } else if (blk < 3072){
    int i = (blk-2560)*256 + tid;     // 128*1024
    int r = i >> 10, k = i & 1023;
    float v = 0.f;
    if (r < 16) v = Bw[k*16 + r];
    else if (r < 32) v = Cw[k*16 + (r-16)];
    bc_dst[(size_t)r*1024 + k] = f2bf(v);
  } else {
    int i = (blk-3072)*256 + tid;
    if (i < 512*16) A_tab[i] = -__expf(A_log[i]);
  }
}

// RMSNorm over rows of 1024 f32 -> bf16
__global__ __launch_bounds__(256) void rmsnorm_k(const float* __restrict__ x, const float* __restrict__ w, u16* __restrict__ out)
{
  const int row = blockIdx.x, tid = threadIdx.x;
  float4 v = ((const float4*)(x + (size_t)row*1024))[tid];
  float s = v.x*v.x + v.y*v.y + v.z*v.z + v.w*v.w;
  #pragma unroll
  for (int o=32;o>0;o>>=1) s += __shfl_down(s, o);
  __shared__ float red[4];
  const int wave = tid>>6, lane = tid&63;
  if (lane==0) red[wave] = s;
  __syncthreads();
  float tot = red[0]+red[1]+red[2]+red[3];
  float sc = rsqrtf(tot*(1.f/1024.f) + 1e-6f);
  float4 wv = ((const float4*)w)[tid];
  ushort4 p; p.x=f2bf(v.x*sc*wv.x); p.y=f2bf(v.y*sc*wv.y); p.z=f2bf(v.z*sc*wv.z); p.w=f2bf(v.w*sc*wv.w);
  ((ushort4*)(out + (size_t)row*1024))[tid] = p;
}

// depthwise causal conv (K=4) + silu gate -> mixed cols 0..511
__global__ __launch_bounds__(256) void conv_k(const u16* __restrict__ P1, const float* __restrict__ kw, u16* __restrict__ mixed)
{
  const int idx = blockIdx.x*256 + threadIdx.x;   // B*C*512
  const int c = idx & 511;
  const int t = (idx>>9) & 2047;
  const int b = idx >> 20;
  const size_t rowb = (size_t)b*2048;
  float g = bf2f(P1[(rowb+t)*1024 + c]);
  float acc = 0.f;
  #pragma unroll
  for (int k=0;k<4;k++){
    int tt = t-3+k;
    if (tt>=0) acc += bf2f(P1[(rowb+tt)*1024 + 512 + c]) * kw[k*512+c];
  }
  mixed[(rowb+t)*1024 + c] = f2bf(silu_(g)*acc);
}

// chunked selective scan: 64 chunks of 32
#define NCH_ 64
#define CHL_ 32
__global__ __launch_bounds__(256) void scan_p1(const float* __restrict__ dt, const u16* __restrict__ P2,
                                               const float* __restrict__ BCs, const float* __restrict__ A_tab,
                                               float* __restrict__ hend, float* __restrict__ aprod)
{
  const int d = blockIdx.x*256 + threadIdx.x;
  const int ch = blockIdx.y, b = blockIdx.z;
  float Ar[16], h[16], ap[16];
  #pragma unroll
  for (int s=0;s<16;s++){ Ar[s] = A_tab[d*16+s]; h[s]=0.f; ap[s]=1.f; }
  const int t0 = ch*CHL_;
  for (int t=0;t<CHL_;t++){
    size_t row = (size_t)b*2048 + t0 + t;
    float dtv = dt[row*512 + d];
    float u = bf2f(P2[row*1024 + d]);
    float du = dtv*u;
    const float* bs = BCs + row*32;
    #pragma unroll
    for (int s=0;s<16;s++){
      float dA = __expf(dtv*Ar[s]);
      h[s] = dA*h[s] + du*bs[s];
      ap[s] *= dA;
    }
  }
  size_t o = ((size_t)((b*512+d)*NCH_ + ch))*16;
  #pragma unroll
  for (int s=0;s<16;s++){ hend[o+s]=h[s]; aprod[o+s]=ap[s]; }
}

// sequential over chunks; rewrites hend in place with chunk-entry states
__global__ __launch_bounds__(256) void scan_p2(float* __restrict__ hend, const float* __restrict__ aprod)
{
  const int g = blockIdx.x*256 + threadIdx.x;   // 32768 = (b*512+d)*16+s
  const int s = g & 15, bd = g >> 4;
  float h = 0.f;
  for (int ch=0; ch<NCH_; ch++){
    size_t o = ((size_t)(bd*NCH_+ch))*16 + s;
    float he = hend[o], ap = aprod[o];
    hend[o] = h;                 // h at chunk entry
    h = ap*h + he;
  }
}

__global__ __launch_bounds__(256) void scan_p3(const float* __restrict__ dt, const u16* __restrict__ P2,
                                               const float* __restrict__ BCs, const float* __restrict__ A_tab,
                                               const float* __restrict__ hin, const float* __restrict__ Dp,
                                               u16* __restrict__ mixed)
{
  const int d = blockIdx.x*256 + threadIdx.x;
  const int ch = blockIdx.y, b = blockIdx.z;
  float Ar[16], h[16];
  size_t o = ((size_t)((b*512+d)*NCH_ + ch))*16;
  #pragma unroll
  for (int s=0;s<16;s++){ Ar[s] = A_tab[d*16+s]; h[s] = hin[o+s]; }
  const float Dd = Dp[d];
  const int t0 = ch*CHL_;
  for (int t=0;t<CHL_;t++){
    size_t row = (size_t)b*2048 + t0 + t;
    float dtv = dt[row*512 + d];
    float u = bf2f(P2[row*1024 + d]);
    float zv = bf2f(P2[row*1024 + 512 + d]);
    float du = dtv*u;
    const float* bs = BCs + row*32;
    const float* cs = bs + 16;
    float y = 0.f;
    #pragma unroll
    for (int s=0;s<16;s++){
      float dA = __expf(dtv*Ar[s]);
      h[s] = dA*h[s] + du*bs[s];
      y += h[s]*cs[s];
    }
    float outv = (y + Dd*u)*silu_(zv);
    mixed[row*1024 + 512 + d] = f2bf(outv);
  }
}

extern "C" void kernel_launch(void* const* d_in, const int* in_sizes, int n_in,
                              void* d_out, int out_size, void* d_ws, size_t ws_size,
                              hipStream_t stream)
{
  const float* x          = (const float*)d_in[0];
  const float* velocity   = (const float*)d_in[1];
  const float* v_hat      = (const float*)d_in[2];
  const float* delta_W    = (const float*)d_in[3];
  const float* pre_norm_w = (const float*)d_in[4];
  const float* ffn_norm_w = (const float*)d_in[5];
  const float* conv_in_w  = (const float*)d_in[6];
  const float* conv_kw    = (const float*)d_in[7];
  const float* ssm_in_w   = (const float*)d_in[8];
  const float* ssm_dt_w   = (const float*)d_in[9];
  const float* ssm_dt_b   = (const float*)d_in[10];
  const float* ssm_A_log  = (const float*)d_in[11];
  const float* ssm_B_w    = (const float*)d_in[12];
  const float* ssm_C_w    = (const float*)d_in[13];
  const float* ssm_D      = (const float*)d_in[14];
  const float* out_proj_w = (const float*)d_in[15];
  const float* log_beta   = (const float*)d_in[16];
  const float* gate_up_w  = (const float*)d_in[17];
  const float* ffn_down_w = (const float*)d_in[18];
  const float* ffn_tgt_w  = (const float*)d_in[19];
  const float* log_gamma  = (const float*)d_in[20];
  const float* log_eta    = (const float*)d_in[21];

  float* out_x     = (float*)d_out;
  float* out_vel   = out_x + (size_t)ROWS_*D_;
  float* out_delta = out_vel + (size_t)ROWS_*D_;

  char* wsp = (char*)d_ws;
  size_t off = 0;
  auto alloc = [&](size_t bytes)->char*{ char* p = wsp + off; off += (bytes + 255) & ~(size_t)255; return p; };

  u16* Wti        = (u16*)alloc((size_t)2688*1024*2);   // combined in-proj weight^T
  u16* out_proj_t = (u16*)alloc((size_t)1024*1024*2);
  u16* gate_up_t  = (u16*)alloc((size_t)5120*1024*2);   // 16-granular interleave
  u16* target_t   = (u16*)alloc((size_t)2560*1024*2);
  u16* weff_t     = (u16*)alloc((size_t)1024*2560*2);
  float* A_tab    = (float*)alloc((size_t)512*16*4);
  u16* xn         = (u16*)alloc((size_t)ROWS_*1024*2);
  u16* P1         = (u16*)alloc((size_t)ROWS_*1024*2);
  u16* P2         = (u16*)alloc((size_t)ROWS_*1024*2);
  float* dtbuf    = (float*)alloc((size_t)ROWS_*512*4);
  float* BCs      = (float*)alloc((size_t)ROWS_*32*4);
  float* hend     = (float*)alloc((size_t)4*512*NCH_*16*4);
  float* aprod    = (float*)alloc((size_t)4*512*NCH_*16*4);
  u16* mixed      = (u16*)alloc((size_t)ROWS_*1024*2);
  u16* ffn_in     = (u16*)alloc((size_t)ROWS_*1024*2);
  u16* zbuf       = (u16*)alloc((size_t)ROWS_*2560*2);
  u16* T1t        = (u16*)alloc((size_t)2560*ROWS_*2);
  u16* ffn_inT    = xn;     // reuse: xn dead after INTRANS GEMM
  u16* vhat_bf    = mixed;  // reuse: consumed by INTRANS before conv/scan write mixed

  dim3 tb(32,8);
  // weight prep
  prep_transposes<<<dim3(160,32,6), tb, 0, stream>>>(conv_in_w, ssm_in_w, ssm_dt_w, out_proj_w,
      ffn_tgt_w, gate_up_w, Wti, out_proj_t, target_t, gate_up_t);
  weff_transpose<<<dim3(32,80), tb, 0, stream>>>(ffn_down_w, delta_W, weff_t);
  prep_small<<<3104, 256, 0, stream>>>(delta_W, log_gamma, ssm_B_w, ssm_C_w, ssm_A_log,
      out_delta, Wti + (size_t)2560*1024, A_tab);
  cvt_bf16x4<<<8192, 256, 0, stream>>>(v_hat, vhat_bf, ROWS_*1024/4);

  // pre-norm + fused {input projections | v_hat_proj^T}
  rmsnorm_k<<<ROWS_, 256, 0, stream>>>(x, pre_norm_w, xn);
  gemm128<EPI_INTRANS><<<dim3(41,64), 256, 0, stream>>>(xn, Wti, ROWS_,2688,1024,1024,
      dtbuf, BCs, ssm_dt_b, nullptr, nullptr, P1, P2, T1t, vhat_bf, target_t);

  // conv branch + ssm branch -> mixed
  conv_k<<<16384, 256, 0, stream>>>(P1, conv_kw, mixed);
  scan_p1<<<dim3(2,NCH_,4), 256, 0, stream>>>(dtbuf, P2, BCs, A_tab, hend, aprod);
  scan_p2<<<128, 256, 0, stream>>>(hend, aprod);
  scan_p3<<<dim3(2,NCH_,4), 256, 0, stream>>>(dtbuf, P2, BCs, A_tab, hend, ssm_D, mixed);

  // out_proj + momentum residual -> velocity, x_new
  gemm128<EPI_MOM><<<dim3(8,64), 256, 0, stream>>>(mixed, out_proj_t, ROWS_,1024,1024,1024,
      out_vel, out_x, velocity, x, log_beta, nullptr, nullptr, nullptr, nullptr, nullptr);

  // FFN
  rmsnorm_k<<<ROWS_, 256, 0, stream>>>(out_x, ffn_norm_w, ffn_in);
  transpose_bf16<<<dim3(32,256), tb, 0, stream>>>(ffn_in, ffn_inT, ROWS_, 1024);

  // fused gate/up (16-granular interleave) -> z = silu(gate)*up
  gemm128<EPI_SWIGLU><<<dim3(40,64), 256, 0, stream>>>(ffn_in, gate_up_t, ROWS_,5120,1024,1024,
      nullptr,nullptr,nullptr,nullptr,nullptr, zbuf, nullptr, nullptr, nullptr, nullptr);

  // fused {down-proj atomic into final x | delta update atomic into out_delta}
  gemm128<EPI_DOWNDELTA><<<dim3(16,64,4), 256, 0, stream>>>(zbuf, weff_t, ROWS_,1024,2560,1280,
      out_x, out_delta, nullptr, nullptr, log_eta, nullptr, nullptr, nullptr, T1t, ffn_inT);
}

// Round 5
// 823.084 us; speedup vs baseline: 1.3863x; 1.0661x over previous
//
#include <hip/hip_runtime.h>
#include <stdint.h>
#include <stddef.h>

#define B_ 4
#define C_ 2048
#define D_ 1024
#define FFN_ 2560
#define ROWS_ 8192   // B_*C_

typedef unsigned short u16;
typedef short bf16x8 __attribute__((ext_vector_type(8)));
typedef float f32x4 __attribute__((ext_vector_type(4)));

__device__ __forceinline__ float bf2f(u16 x){ union { unsigned u; float f; } v; v.u = ((unsigned)x)<<16; return v.f; }
__device__ __forceinline__ u16 f2bf(float f){ union { float f; unsigned u; } v; v.f = f; unsigned r = v.u + 0x7fffu + ((v.u>>16)&1u); return (u16)(r>>16); }
__device__ __forceinline__ float sigm_(float x){ return 1.f/(1.f+__expf(-x)); }
__device__ __forceinline__ float silu_(float x){ return x/(1.f+__expf(-x)); }
__device__ __forceinline__ float softplus_(float x){ return (x>15.f)? x : log1pf(__expf(x)); }

__device__ __forceinline__ void async16(u16* lds_base, const u16* g){
  __builtin_amdgcn_global_load_lds((const __attribute__((address_space(1))) unsigned int*)g,
                                   (__attribute__((address_space(3))) unsigned int*)lds_base,
                                   16, 0, 0);
}

// ---------------- GEMM: C(MxN) = A(MxK,row-major bf16) * Bt(NxK,row-major bf16)^T
// BK=64 K-loop; XOR-swizzled k-group LDS layout (slot s of row r holds k-group s^(r&7)).
#define EPI_INTRANS 0   // fused: x<21 -> input projections; x>=21 -> v_hat_proj^T
#define EPI_MOM     1
#define EPI_SWIGLU  2
#define EPI_DOWN    3   // read-modify-write add into out_x (no split-K)
#define EPI_DELTA   4   // split-K atomic into out_delta

template<int EPI>
__global__ __launch_bounds__(256)
void gemm128(const u16* __restrict__ A, const u16* __restrict__ Bt,
             int M, int N, int K, int ksplit,
             float* __restrict__ f0, float* __restrict__ f1,
             const float* __restrict__ c0, const float* __restrict__ c1, const float* __restrict__ c2,
             u16* __restrict__ h0, u16* __restrict__ h1, u16* __restrict__ h2,
             const u16* __restrict__ a2, const u16* __restrict__ b2)
{
  __shared__ u16 smem[16384];          // As = [0:8192], Bs = [8192:16384]  (128x64 each)
  u16* As = smem;
  u16* Bs = smem + 8192;
  const int tid  = threadIdx.x;
  const int wave = tid>>6, lane = tid&63;

  int bx = blockIdx.x;
  bool alt = false;
  if constexpr (EPI == EPI_INTRANS){
    if (bx >= 21){ alt = true; bx -= 21; A = a2; Bt = b2; }
  }
  const int bm = blockIdx.y*128, bn = bx*128;

  // staging: per wave 4 A-instrs + 4 B-instrs; instr q covers rows wave*32+q*8 .. +7
  const int lr8  = lane>>3;                  // row within 8-row chunk
  const int kswz = ((lane&7) ^ lr8)*8;       // swizzled k-group fetched by this lane
  const u16* aG[4]; const u16* bG[4]; u16* aL[4]; u16* bL[4];
  #pragma unroll
  for (int q=0;q<4;q++){
    const int r = wave*32 + q*8 + lr8;
    aG[q] = A  + (size_t)(bm + r)*K + kswz;
    bG[q] = Bt + (size_t)(bn + r)*K + kswz;
    aL[q] = As + (wave*32 + q*8)*64;
    bL[q] = Bs + (wave*32 + q*8)*64;
  }
  const int wr = wave>>1, wc = wave&1;
  const int mrow = lane&15, quad = lane>>4;
  const int swz8 = (mrow&7);

  f32x4 acc[4][4];
  #pragma unroll
  for (int i=0;i<4;i++)
    #pragma unroll
    for (int j=0;j<4;j++) acc[i][j] = (f32x4){0.f,0.f,0.f,0.f};

  const int kbeg = blockIdx.z * ksplit;
  const int kend = kbeg + ksplit;
  for (int k0=kbeg; k0<kend; k0+=64){
    __syncthreads();
    #pragma unroll
    for (int q=0;q<4;q++) async16(aL[q], aG[q] + k0);
    #pragma unroll
    for (int q=0;q<4;q++) async16(bL[q], bG[q] + k0);
    __syncthreads();
    #pragma unroll
    for (int kk=0; kk<64; kk+=32){
      bf16x8 af[4], bfv[4];
      const int gq = (kk>>3) + quad;
      const int pos = (gq ^ swz8)*8;
      #pragma unroll
      for (int i=0;i<4;i++) af[i]  = *(const bf16x8*)(As + (wr*64+i*16+mrow)*64 + pos);
      #pragma unroll
      for (int j=0;j<4;j++) bfv[j] = *(const bf16x8*)(Bs + (wc*64+j*16+mrow)*64 + pos);
      #pragma unroll
      for (int i=0;i<4;i++)
        #pragma unroll
        for (int j=0;j<4;j++)
          acc[i][j] = __builtin_amdgcn_mfma_f32_16x16x32_bf16(af[i], bfv[j], acc[i][j], 0,0,0);
    }
  }

  if constexpr (EPI == EPI_INTRANS){
    if (alt){
      // v_hat_proj^T: LDS-staged transposed write, coalesced global stores (cols of T1t, stride 8192)
      __syncthreads();
      #pragma unroll
      for (int h=0; h<4; h++){
        const int hw = h>>1, j0 = (h&1)*2;
        if (wc == hw){
          #pragma unroll
          for (int i=0;i<4;i++){
            const int rbase = wr*64 + i*16 + quad*4;
            #pragma unroll
            for (int jj=0;jj<2;jj++){
              const int j = j0+jj;
              const int cl = jj*16 + mrow;
              f32x4 v = acc[i][j];
              #pragma unroll
              for (int t=0;t<4;t++) smem[cl*132 + rbase + t] = f2bf(v[t]);
            }
          }
        }
        __syncthreads();
        {
          const int cl2 = tid>>3, m0 = (tid&7)*16;
          const int col = bn + h*32 + cl2;
          const ushort4* s4 = (const ushort4*)(smem + cl2*132 + m0);
          ushort4* d4 = (ushort4*)(h2 + (size_t)col*8192 + bm + m0);
          #pragma unroll
          for (int q=0;q<4;q++) d4[q] = s4[q];
        }
        __syncthreads();
      }
    } else {
      // input projections: N=2688 = [P1 1024 | P2 1024 | dt 512 | BC 32 (+96 pad)]
      #pragma unroll
      for (int i=0;i<4;i++){
        const int row0 = bm + wr*64 + i*16 + quad*4;
        #pragma unroll
        for (int j=0;j<4;j++){
          const int col = bn + wc*64 + j*16 + mrow;
          f32x4 v = acc[i][j];
          if (col < 1024){
            #pragma unroll
            for (int t=0;t<4;t++) h0[(size_t)(row0+t)*1024 + col] = f2bf(v[t]);
          } else if (col < 2048){
            #pragma unroll
            for (int t=0;t<4;t++) h1[(size_t)(row0+t)*1024 + (col-1024)] = f2bf(v[t]);
          } else if (col < 2560){
            const float b = c0[col-2048];
            #pragma unroll
            for (int t=0;t<4;t++) f0[(size_t)(row0+t)*512 + (col-2048)] = softplus_(v[t]+b);
          } else {
            const int cl = col - 2560;
            if (cl < 32){
              #pragma unroll
              for (int t=0;t<4;t++) f1[(size_t)(row0+t)*32 + cl] = v[t];
            }
          }
        }
      }
    }
  } else if constexpr (EPI == EPI_MOM){
    const float beta = sigm_(c2[0]);
    #pragma unroll
    for (int i=0;i<4;i++){
      const int row0 = bm + wr*64 + i*16 + quad*4;
      #pragma unroll
      for (int j=0;j<4;j++){
        const int col = bn + wc*64 + j*16 + mrow;
        f32x4 v = acc[i][j];
        #pragma unroll
        for (int t=0;t<4;t++){
          size_t idx = (size_t)(row0+t)*1024 + col;
          float vel = beta*c0[idx] + v[t];
          f0[idx] = vel;
          f1[idx] = c1[idx] + vel;
        }
      }
    }
  } else if constexpr (EPI == EPI_SWIGLU){
    #pragma unroll
    for (int i=0;i<4;i++){
      const int row0 = bm + wr*64 + i*16 + quad*4;
      #pragma unroll
      for (int jp=0;jp<4;jp+=2){
        f32x4 g = acc[i][jp];
        f32x4 u = acc[i][jp+1];
        const int o = (((bn + wc*64 + jp*16)>>5)<<4) + mrow;   // [0,2560)
        #pragma unroll
        for (int t=0;t<4;t++) h0[(size_t)(row0+t)*2560 + o] = f2bf(silu_(g[t])*u[t]);
      }
    }
  } else if constexpr (EPI == EPI_DOWN){
    #pragma unroll
    for (int i=0;i<4;i++){
      const int row0 = bm + wr*64 + i*16 + quad*4;
      #pragma unroll
      for (int j=0;j<4;j++){
        const int col = bn + wc*64 + j*16 + mrow;
        f32x4 v = acc[i][j];
        #pragma unroll
        for (int t=0;t<4;t++){
          size_t idx = (size_t)(row0+t)*1024 + col;
          f0[idx] = f0[idx] + v[t];
        }
      }
    }
  } else if constexpr (EPI == EPI_DELTA){
    const float e = softplus_(c2[0])*0.25f;
    #pragma unroll
    for (int i=0;i<4;i++){
      const int row0 = bm + wr*64 + i*16 + quad*4;
      #pragma unroll
      for (int j=0;j<4;j++){
        const int col = bn + wc*64 + j*16 + mrow;
        f32x4 v = acc[i][j];
        #pragma unroll
        for (int t=0;t<4;t++) atomicAdd(&f0[(size_t)(row0+t)*1024 + col], e*v[t]);
      }
    }
  }
}

// ---------------- combined weight transposes (z-indexed)
__global__ void prep_transposes(const float* __restrict__ conv_in_w, const float* __restrict__ ssm_in_w,
                                const float* __restrict__ ssm_dt_w, const float* __restrict__ out_proj_w,
                                const float* __restrict__ ffn_tgt_w, const float* __restrict__ gate_up_w,
                                u16* __restrict__ Wti, u16* __restrict__ out_proj_t,
                                u16* __restrict__ target_t, u16* __restrict__ gate_up_t)
{
  const int z = blockIdx.z;
  const float* W; u16* Wt; int N; bool gu = false;
  switch(z){
    case 0: W=conv_in_w;  Wt=Wti;                       N=1024; break;
    case 1: W=ssm_in_w;   Wt=Wti + (size_t)1024*1024;   N=1024; break;
    case 2: W=ssm_dt_w;   Wt=Wti + (size_t)2048*1024;   N=512;  break;
    case 3: W=out_proj_w; Wt=out_proj_t;                N=1024; break;
    case 4: W=ffn_tgt_w;  Wt=target_t;                  N=2560; break;
    default: W=gate_up_w; Wt=gate_up_t;                 N=5120; gu=true; break;
  }
  const int c0 = blockIdx.x*32, r0 = blockIdx.y*32;
  if (c0 >= N) return;
  __shared__ float tile[32][33];
  const int tx = threadIdx.x, ty = threadIdx.y;
  #pragma unroll
  for (int i=0;i<4;i++) tile[ty+8*i][tx] = W[(size_t)(r0+ty+8*i)*N + c0+tx];
  __syncthreads();
  #pragma unroll
  for (int i=0;i<4;i++){
    const int c = c0+ty+8*i;
    int n;
    if (gu){
      if (c < 2560) n = ((c>>4)<<5) | (c&15);
      else { int o = c-2560; n = ((o>>4)<<5) | 16 | (o&15); }
    } else n = c;
    Wt[(size_t)n*1024 + r0+tx] = f2bf(tile[tx][ty+8*i]);
  }
}

// W_eff = ffn_down + delta_W, transposed: (2560x1024) -> (1024x2560) bf16
__global__ void weff_transpose(const float* __restrict__ Wa, const float* __restrict__ Wb, u16* __restrict__ Wt)
{
  __shared__ float tile[32][33];
  const int tx = threadIdx.x, ty = threadIdx.y;
  const int c0 = blockIdx.x*32, r0 = blockIdx.y*32;
  #pragma unroll
  for (int i=0;i<4;i++){
    size_t idx = (size_t)(r0+ty+8*i)*1024 + c0+tx;
    tile[ty+8*i][tx] = Wa[idx] + Wb[idx];
  }
  __syncthreads();
  #pragma unroll
  for (int i=0;i<4;i++) Wt[(size_t)(c0+ty+8*i)*2560 + r0+tx] = f2bf(tile[tx][ty+8*i]);
}

// bf16 transpose (in: R x Cc -> out: Cc x R)
__global__ void transpose_bf16(const u16* __restrict__ in, u16* __restrict__ out, int R, int Cc)
{
  __shared__ u16 tile[32][33];
  const int tx = threadIdx.x, ty = threadIdx.y;
  const int c0 = blockIdx.x*32, r0 = blockIdx.y*32;
  #pragma unroll
  for (int i=0;i<4;i++) tile[ty+8*i][tx] = in[(size_t)(r0+ty+8*i)*Cc + c0+tx];
  __syncthreads();
  #pragma unroll
  for (int i=0;i<4;i++) out[(size_t)(c0+ty+8*i)*R + r0+tx] = tile[tx][ty+8*i];
}

__global__ void cvt_bf16x4(const float* __restrict__ in, u16* __restrict__ out, int n4)
{
  int i = blockIdx.x*256 + threadIdx.x;
  if (i < n4){
    float4 v = ((const float4*)in)[i];
    ushort4 p; p.x=f2bf(v.x); p.y=f2bf(v.y); p.z=f2bf(v.z); p.w=f2bf(v.w);
    ((ushort4*)out)[i] = p;
  }
}

// merged: delta_init (blocks [0,2560)) | B/C weight pack (blocks [2560,3072)) | A_tab (blocks [3072,3104))
__global__ void prep_small(const float* __restrict__ dW, const float* __restrict__ lg,
                           const float* __restrict__ Bw, const float* __restrict__ Cw,
                           const float* __restrict__ A_log,
                           float* __restrict__ out_delta, u16* __restrict__ bc_dst,
                           float* __restrict__ A_tab)
{
  const int blk = blockIdx.x, tid = threadIdx.x;
  if (blk < 2560){
    int i = blk*256 + tid;            // over 2560*1024/4 float4
    float g = sigm_(lg[0]);
    float4 v = ((const float4*)dW)[i];
    float4 r; r.x=g*v.x; r.y=g*v.y; r.z=g*v.z; r.w=g*v.w;
    ((float4*)out_delta)[i] = r;
  } else if (blk < 3072){
    int i = (blk-2560)*256 + tid;     // 128*1024
    int r = i >> 10, k = i & 1023;
    float v = 0.f;
    if (r < 16) v = Bw[k*16 + r];
    else if (r < 32) v = Cw[k*16 + (r-16)];
    bc_dst[(size_t)r*1024 + k] = f2bf(v);
  } else {
    int i = (blk-3072)*256 + tid;
    if (i < 512*16) A_tab[i] = -__expf(A_log[i]);
  }
}

// RMSNorm over rows of 1024 f32 -> bf16
__global__ __launch_bounds__(256) void rmsnorm_k(const float* __restrict__ x, const float* __restrict__ w, u16* __restrict__ out)
{
  const int row = blockIdx.x, tid = threadIdx.x;
  float4 v = ((const float4*)(x + (size_t)row*1024))[tid];
  float s = v.x*v.x + v.y*v.y + v.z*v.z + v.w*v.w;
  #pragma unroll
  for (int o=32;o>0;o>>=1) s += __shfl_down(s, o);
  __shared__ float red[4];
  const int wave = tid>>6, lane = tid&63;
  if (lane==0) red[wave] = s;
  __syncthreads();
  float tot = red[0]+red[1]+red[2]+red[3];
  float sc = rsqrtf(tot*(1.f/1024.f) + 1e-6f);
  float4 wv = ((const float4*)w)[tid];
  ushort4 p; p.x=f2bf(v.x*sc*wv.x); p.y=f2bf(v.y*sc*wv.y); p.z=f2bf(v.z*sc*wv.z); p.w=f2bf(v.w*sc*wv.w);
  ((ushort4*)(out + (size_t)row*1024))[tid] = p;
}

// depthwise causal conv (K=4) + silu gate -> mixed cols 0..511
__global__ __launch_bounds__(256) void conv_k(const u16* __restrict__ P1, const float* __restrict__ kw, u16* __restrict__ mixed)
{
  const int idx = blockIdx.x*256 + threadIdx.x;   // B*C*512
  const int c = idx & 511;
  const int t = (idx>>9) & 2047;
  const int b = idx >> 20;
  const size_t rowb = (size_t)b*2048;
  float g = bf2f(P1[(rowb+t)*1024 + c]);
  float acc = 0.f;
  #pragma unroll
  for (int k=0;k<4;k++){
    int tt = t-3+k;
    if (tt>=0) acc += bf2f(P1[(rowb+tt)*1024 + 512 + c]) * kw[k*512+c];
  }
  mixed[(rowb+t)*1024 + c] = f2bf(silu_(g)*acc);
}

// chunked selective scan: 64 chunks of 32
#define NCH_ 64
#define CHL_ 32
__global__ __launch_bounds__(256) void scan_p1(const float* __restrict__ dt, const u16* __restrict__ P2,
                                               const float* __restrict__ BCs, const float* __restrict__ A_tab,
                                               float* __restrict__ hend, float* __restrict__ aprod)
{
  const int d = blockIdx.x*256 + threadIdx.x;
  const int ch = blockIdx.y, b = blockIdx.z;
  float Ar[16], h[16], ap[16];
  #pragma unroll
  for (int s=0;s<16;s++){ Ar[s] = A_tab[d*16+s]; h[s]=0.f; ap[s]=1.f; }
  const int t0 = ch*CHL_;
  for (int t=0;t<CHL_;t++){
    size_t row = (size_t)b*2048 + t0 + t;
    float dtv = dt[row*512 + d];
    float u = bf2f(P2[row*1024 + d]);
    float du = dtv*u;
    const float* bs = BCs + row*32;
    #pragma unroll
    for (int s=0;s<16;s++){
      float dA = __expf(dtv*Ar[s]);
      h[s] = dA*h[s] + du*bs[s];
      ap[s] *= dA;
    }
  }
  size_t o = ((size_t)((b*512+d)*NCH_ + ch))*16;
  #pragma unroll
  for (int s=0;s<16;s++){ hend[o+s]=h[s]; aprod[o+s]=ap[s]; }
}

// sequential over chunks; rewrites hend in place with chunk-entry states
__global__ __launch_bounds__(256) void scan_p2(float* __restrict__ hend, const float* __restrict__ aprod)
{
  const int g = blockIdx.x*256 + threadIdx.x;   // 32768 = (b*512+d)*16+s
  const int s = g & 15, bd = g >> 4;
  float h = 0.f;
  for (int ch=0; ch<NCH_; ch++){
    size_t o = ((size_t)(bd*NCH_+ch))*16 + s;
    float he = hend[o], ap = aprod[o];
    hend[o] = h;                 // h at chunk entry
    h = ap*h + he;
  }
}

__global__ __launch_bounds__(256) void scan_p3(const float* __restrict__ dt, const u16* __restrict__ P2,
                                               const float* __restrict__ BCs, const float* __restrict__ A_tab,
                                               const float* __restrict__ hin, const float* __restrict__ Dp,
                                               u16* __restrict__ mixed)
{
  const int d = blockIdx.x*256 + threadIdx.x;
  const int ch = blockIdx.y, b = blockIdx.z;
  float Ar[16], h[16];
  size_t o = ((size_t)((b*512+d)*NCH_ + ch))*16;
  #pragma unroll
  for (int s=0;s<16;s++){ Ar[s] = A_tab[d*16+s]; h[s] = hin[o+s]; }
  const float Dd = Dp[d];
  const int t0 = ch*CHL_;
  for (int t=0;t<CHL_;t++){
    size_t row = (size_t)b*2048 + t0 + t;
    float dtv = dt[row*512 + d];
    float u = bf2f(P2[row*1024 + d]);
    float zv = bf2f(P2[row*1024 + 512 + d]);
    float du = dtv*u;
    const float* bs = BCs + row*32;
    const float* cs = bs + 16;
    float y = 0.f;
    #pragma unroll
    for (int s=0;s<16;s++){
      float dA = __expf(dtv*Ar[s]);
      h[s] = dA*h[s] + du*bs[s];
      y += h[s]*cs[s];
    }
    float outv = (y + Dd*u)*silu_(zv);
    mixed[row*1024 + 512 + d] = f2bf(outv);
  }
}

extern "C" void kernel_launch(void* const* d_in, const int* in_sizes, int n_in,
                              void* d_out, int out_size, void* d_ws, size_t ws_size,
                              hipStream_t stream)
{
  const float* x          = (const float*)d_in[0];
  const float* velocity   = (const float*)d_in[1];
  const float* v_hat      = (const float*)d_in[2];
  const float* delta_W    = (const float*)d_in[3];
  const float* pre_norm_w = (const float*)d_in[4];
  const float* ffn_norm_w = (const float*)d_in[5];
  const float* conv_in_w  = (const float*)d_in[6];
  const float* conv_kw    = (const float*)d_in[7];
  const float* ssm_in_w   = (const float*)d_in[8];
  const float* ssm_dt_w   = (const float*)d_in[9];
  const float* ssm_dt_b   = (const float*)d_in[10];
  const float* ssm_A_log  = (const float*)d_in[11];
  const float* ssm_B_w    = (const float*)d_in[12];
  const float* ssm_C_w    = (const float*)d_in[13];
  const float* ssm_D      = (const float*)d_in[14];
  const float* out_proj_w = (const float*)d_in[15];
  const float* log_beta   = (const float*)d_in[16];
  const float* gate_up_w  = (const float*)d_in[17];
  const float* ffn_down_w = (const float*)d_in[18];
  const float* ffn_tgt_w  = (const float*)d_in[19];
  const float* log_gamma  = (const float*)d_in[20];
  const float* log_eta    = (const float*)d_in[21];

  float* out_x     = (float*)d_out;
  float* out_vel   = out_x + (size_t)ROWS_*D_;
  float* out_delta = out_vel + (size_t)ROWS_*D_;

  char* wsp = (char*)d_ws;
  size_t off = 0;
  auto alloc = [&](size_t bytes)->char*{ char* p = wsp + off; off += (bytes + 255) & ~(size_t)255; return p; };

  u16* Wti        = (u16*)alloc((size_t)2688*1024*2);   // combined in-proj weight^T
  u16* out_proj_t = (u16*)alloc((size_t)1024*1024*2);
  u16* gate_up_t  = (u16*)alloc((size_t)5120*1024*2);   // 16-granular interleave
  u16* target_t   = (u16*)alloc((size_t)2560*1024*2);
  u16* weff_t     = (u16*)alloc((size_t)1024*2560*2);
  float* A_tab    = (float*)alloc((size_t)512*16*4);
  u16* xn         = (u16*)alloc((size_t)ROWS_*1024*2);
  u16* P1         = (u16*)alloc((size_t)ROWS_*1024*2);
  u16* P2         = (u16*)alloc((size_t)ROWS_*1024*2);
  float* dtbuf    = (float*)alloc((size_t)ROWS_*512*4);
  float* BCs      = (float*)alloc((size_t)ROWS_*32*4);
  float* hend     = (float*)alloc((size_t)4*512*NCH_*16*4);
  float* aprod    = (float*)alloc((size_t)4*512*NCH_*16*4);
  u16* mixed      = (u16*)alloc((size_t)ROWS_*1024*2);
  u16* ffn_in     = (u16*)alloc((size_t)ROWS_*1024*2);
  u16* zbuf       = (u16*)alloc((size_t)ROWS_*2560*2);
  u16* T1t        = (u16*)alloc((size_t)2560*ROWS_*2);
  u16* ffn_inT    = xn;     // reuse: xn dead after INTRANS GEMM
  u16* vhat_bf    = mixed;  // reuse: consumed by INTRANS before conv/scan write mixed

  dim3 tb(32,8);
  // weight prep
  prep_transposes<<<dim3(160,32,6), tb, 0, stream>>>(conv_in_w, ssm_in_w, ssm_dt_w, out_proj_w,
      ffn_tgt_w, gate_up_w, Wti, out_proj_t, target_t, gate_up_t);
  weff_transpose<<<dim3(32,80), tb, 0, stream>>>(ffn_down_w, delta_W, weff_t);
  prep_small<<<3104, 256, 0, stream>>>(delta_W, log_gamma, ssm_B_w, ssm_C_w, ssm_A_log,
      out_delta, Wti + (size_t)2560*1024, A_tab);
  cvt_bf16x4<<<8192, 256, 0, stream>>>(v_hat, vhat_bf, ROWS_*1024/4);

  // pre-norm + fused {input projections | v_hat_proj^T}
  rmsnorm_k<<<ROWS_, 256, 0, stream>>>(x, pre_norm_w, xn);
  gemm128<EPI_INTRANS><<<dim3(41,64), 256, 0, stream>>>(xn, Wti, ROWS_,2688,1024,1024,
      dtbuf, BCs, ssm_dt_b, nullptr, nullptr, P1, P2, T1t, vhat_bf, target_t);

  // conv branch + ssm branch -> mixed
  conv_k<<<16384, 256, 0, stream>>>(P1, conv_kw, mixed);
  scan_p1<<<dim3(2,NCH_,4), 256, 0, stream>>>(dtbuf, P2, BCs, A_tab, hend, aprod);
  scan_p2<<<128, 256, 0, stream>>>(hend, aprod);
  scan_p3<<<dim3(2,NCH_,4), 256, 0, stream>>>(dtbuf, P2, BCs, A_tab, hend, ssm_D, mixed);

  // out_proj + momentum residual -> velocity, x_new
  gemm128<EPI_MOM><<<dim3(8,64), 256, 0, stream>>>(mixed, out_proj_t, ROWS_,1024,1024,1024,
      out_vel, out_x, velocity, x, log_beta, nullptr, nullptr, nullptr, nullptr, nullptr);

  // FFN
  rmsnorm_k<<<ROWS_, 256, 0, stream>>>(out_x, ffn_norm_w, ffn_in);
  transpose_bf16<<<dim3(32,256), tb, 0, stream>>>(ffn_in, ffn_inT, ROWS_, 1024);

  // fused gate/up (16-granular interleave) -> z = silu(gate)*up
  gemm128<EPI_SWIGLU><<<dim3(40,64), 256, 0, stream>>>(ffn_in, gate_up_t, ROWS_,5120,1024,1024,
      nullptr,nullptr,nullptr,nullptr,nullptr, zbuf, nullptr, nullptr, nullptr, nullptr);

  // down-proj: no split-K, plain read-add-write into out_x (x + vel already there)
  gemm128<EPI_DOWN><<<dim3(8,64), 256, 0, stream>>>(zbuf, weff_t, ROWS_,1024,2560,2560,
      out_x, nullptr, nullptr, nullptr, nullptr, nullptr, nullptr, nullptr, nullptr, nullptr);

  // delta_W update: split-K x8, atomic into out_delta (pre-initialized g*delta_W)
  gemm128<EPI_DELTA><<<dim3(8,20,8), 256, 0, stream>>>(T1t, ffn_inT, 2560,1024,ROWS_,1024,
      out_delta, nullptr, nullptr, nullptr, log_eta, nullptr, nullptr, nullptr, nullptr, nullptr);
}